// Round 7
// baseline (265.877 us; speedup 1.0000x reference)
//
#include <hip/hip_runtime.h>
#include <cfloat>
#include <cmath>

// ---------------------------------------------------------------------------
// UncertaintyGAT. Round-7: latency/VALU/launch shaving.
//  - agg12 phase1: full-wave head-split (was half-wave idle at deg~32)
//  - agg12 phase2: 16/4/1 unroll, int4/float4 broadcast LDS reads
//  - agg3: 32-lane groups, 8 nodes/block
//  - scanS folded into bucketB (inline masked sum); 3x wswz -> 1 launch
// MFMA split-bf16 GEMMs (r6), LDS-reorder CSR build (r5), bf16 z (r3).
// ---------------------------------------------------------------------------

#define CBG 256
#define CAPC 12288
#define TILE 8192
#define BIMG 10240

typedef __attribute__((ext_vector_type(8))) short short8v;
typedef __attribute__((ext_vector_type(4))) float f32x4;

__device__ __forceinline__ float lrelu(float x) { return x > 0.f ? x : 0.2f * x; }

__device__ __forceinline__ uint32_t bf16_rne(float f) {
  uint32_t u = __float_as_uint(f);
  return (u + 0x7fffu + ((u >> 16) & 1u)) >> 16;
}
__device__ __forceinline__ uint32_t pack_hilo(float v) {
  uint32_t h = bf16_rne(v);
  float r = v - __uint_as_float(h << 16);
  return (h << 16) | bf16_rne(r);
}

// ---------------- CSR build (n < 65536 path) ----------------
__global__ __launch_bounds__(256) void bucketA_kernel(
    const int* __restrict__ src, const int* __restrict__ dst,
    int* __restrict__ scount, uint32_t* __restrict__ tmp, int e, int ncb) {
  __shared__ int cnt[256];
  __shared__ int lscan[256];
  __shared__ int gbase[256];
  __shared__ uint32_t image[TILE];
  const int t = threadIdx.x;
  const int e0 = blockIdx.x * TILE;
  const int ne = min(TILE, e - e0);

  for (int i = t; i < 256; i += 256) cnt[i] = 0;
  __syncthreads();
  for (int i = t; i < ne; i += 256) atomicAdd(&cnt[dst[e0 + i] >> 8], 1);
  __syncthreads();
  if (t < 64) {
    int carry = 0;
    for (int base = 0; base < ncb; base += 64) {
      int idx = base + t;
      int c = (idx < ncb) ? cnt[idx] : 0;
      int v = c;
#pragma unroll
      for (int off = 1; off < 64; off <<= 1) {
        int u = __shfl_up(v, off, 64);
        if (t >= off) v += u;
      }
      if (idx < ncb) lscan[idx] = carry + v - c;
      carry += __shfl(v, 63, 64);
    }
  }
  __syncthreads();
  for (int b = t; b < ncb; b += 256)
    gbase[b] = (cnt[b] > 0) ? atomicAdd(&scount[b], cnt[b]) : 0;
  __syncthreads();
  for (int b = t; b < ncb; b += 256) cnt[b] = 0;
  __syncthreads();
  for (int i = t; i < ne; i += 256) {
    int d = dst[e0 + i], s = src[e0 + i];
    int b = d >> 8;
    int r = atomicAdd(&cnt[b], 1);
    image[lscan[b] + r] =
        (uint32_t)s | ((uint32_t)(d & 255) << 16) | ((uint32_t)b << 24);
  }
  __syncthreads();
  for (int j = t; j < ne; j += 256) {
    uint32_t w = image[j];
    int b = w >> 24;
    int pos = gbase[b] + (j - lscan[b]);
    if (pos < CAPC) tmp[(size_t)b * CAPC + pos] = w & 0xFFFFFFu;
  }
}

// bucketB with inline base computation (masked sum over scount[0..b))
__global__ __launch_bounds__(256) void bucketB_kernel(
    const uint32_t* __restrict__ tmp, const int* __restrict__ scount,
    int* __restrict__ row_start, int* __restrict__ csr_src, int n, int ncb, int e) {
  __shared__ int cnt[256];
  __shared__ int cur[256];
  __shared__ int wsum[4];
  __shared__ int s_base;
  __shared__ uint32_t image[BIMG];
  const int b = blockIdx.x, t = threadIdx.x, lane = t & 63, wid = t >> 6;

  if (t < 64) {
    int part = 0;
    for (int idx = lane; idx < b; idx += 64) part += scount[idx];
#pragma unroll
    for (int off = 32; off; off >>= 1) part += __shfl_xor(part, off, 64);
    if (lane == 0) s_base = part;
  }
  cnt[t] = 0;
  __syncthreads();
  const int total = min(scount[b], CAPC);
  const int base = s_base;
  const uint32_t* strm = tmp + (size_t)b * CAPC;

  for (int i = t; i < total; i += 256) atomicAdd(&cnt[(strm[i] >> 16) & 255], 1);
  __syncthreads();
  int c = cnt[t], v = c;
#pragma unroll
  for (int off = 1; off < 64; off <<= 1) {
    int u = __shfl_up(v, off, 64);
    if (lane >= off) v += u;
  }
  if (lane == 63) wsum[wid] = v;
  __syncthreads();
  if (t == 0) {
    int acc = 0;
#pragma unroll
    for (int w = 0; w < 4; w++) { int x = wsum[w]; wsum[w] = acc; acc += x; }
  }
  __syncthreads();
  int ex = wsum[wid] + v - c;
  cur[t] = ex;
  int d = b * CBG + t;
  if (d < n) row_start[d] = base + ex;
  if (b == 0 && t == 0) row_start[n] = e;
  __syncthreads();
  for (int i = t; i < total; i += 256) {
    uint32_t w = strm[i];
    int dl = (w >> 16) & 255;
    int pos = atomicAdd(&cur[dl], 1);
    if (pos < BIMG) image[pos] = w & 0xFFFFu;
    else csr_src[base + pos] = (int)(w & 0xFFFFu);
  }
  __syncthreads();
  const int lim = total < BIMG ? total : BIMG;
  for (int j = t; j < lim; j += 256) csr_src[base + j] = (int)image[j];
}

// ---------------- fallback path (n >= 65536) ----------------
__global__ void hist_kernel(const int* __restrict__ dst, int* __restrict__ cnt, int e) {
  for (int i = blockIdx.x * blockDim.x + threadIdx.x; i < e; i += gridDim.x * blockDim.x)
    atomicAdd(&cnt[dst[i]], 1);
}
__global__ void scatter_kernel(const int* __restrict__ src, const int* __restrict__ dst,
                               const int* __restrict__ row_start, int* __restrict__ cursor,
                               int* __restrict__ csr_src, int e) {
  for (int i = blockIdx.x * blockDim.x + threadIdx.x; i < e; i += gridDim.x * blockDim.x) {
    int d = dst[i];
    int pos = atomicAdd(&cursor[d], 1);
    csr_src[row_start[d] + pos] = src[i];
  }
}
__global__ __launch_bounds__(1024) void scan1_kernel(const int* __restrict__ cnt,
                                                     int* __restrict__ row_start,
                                                     int* __restrict__ bsum, int n) {
  __shared__ int wsum[16];
  const int t = threadIdx.x, lane = t & 63, wid = t >> 6;
  int i = blockIdx.x * 1024 + t;
  int c = (i < n) ? cnt[i] : 0;
  int v = c;
#pragma unroll
  for (int off = 1; off < 64; off <<= 1) {
    int u = __shfl_up(v, off, 64);
    if (lane >= off) v += u;
  }
  if (lane == 63) wsum[wid] = v;
  __syncthreads();
  if (t == 0) {
    int acc = 0;
#pragma unroll
    for (int w = 0; w < 16; w++) { int x = wsum[w]; wsum[w] = acc; acc += x; }
    bsum[blockIdx.x] = acc;
  }
  __syncthreads();
  if (i < n) row_start[i] = wsum[wid] + v - c;
}
__global__ __launch_bounds__(64) void scan2_kernel(int* __restrict__ bsum, int nb) {
  const int lane = threadIdx.x;
  int carry = 0;
  for (int base = 0; base < nb; base += 64) {
    int idx = base + lane;
    int c = (idx < nb) ? bsum[idx] : 0;
    int v = c;
#pragma unroll
    for (int off = 1; off < 64; off <<= 1) {
      int u = __shfl_up(v, off, 64);
      if (lane >= off) v += u;
    }
    if (idx < nb) bsum[idx] = carry + v - c;
    carry += __shfl(v, 63, 64);
  }
}
__global__ void scan3_kernel(int* __restrict__ row_start, const int* __restrict__ bsum,
                             int n, int e) {
  int i = blockIdx.x * blockDim.x + threadIdx.x;
  if (i < n) row_start[i] += bsum[i >> 10];
  if (i == 0) row_start[n] = e;
}

// ---------------- W pre-split+swizzle, all 3 weights in one launch ---------
__global__ __launch_bounds__(256) void wswz3_kernel(
    const float* __restrict__ W0, const float* __restrict__ W1,
    const float* __restrict__ W2, short* __restrict__ Whi0,
    short* __restrict__ Wlo0, short* __restrict__ Whi1, short* __restrict__ Wlo1,
    short* __restrict__ Whi2, short* __restrict__ Wlo2) {
  int which = blockIdx.x >> 3;
  const float* W = which == 0 ? W0 : (which == 1 ? W1 : W2);
  short* Whi = which == 0 ? Whi0 : (which == 1 ? Whi1 : Whi2);
  short* Wlo = which == 0 ? Wlo0 : (which == 1 ? Wlo1 : Wlo2);
  int fid = (blockIdx.x & 7) * 256 + threadIdx.x;  // 0..2047
  int lane = fid & 63;
  int cq = fid >> 6;
  int q = cq >> 3, c = cq & 7;
  int col = c * 16 + (lane & 15);
  int k0 = q * 32 + (lane >> 4) * 8;
#pragma unroll
  for (int j = 0; j < 8; j++) {
    float v = W[(k0 + j) * 128 + col];
    uint32_t h = bf16_rne(v);
    float r = v - __uint_as_float(h << 16);
    Whi[fid * 8 + j] = (short)h;
    Wlo[fid * 8 + j] = (short)bf16_rne(r);
  }
}

// ---------------- MFMA GEMM: 64 nodes/block, N=128, K=128 ------------------
template <int MODE>
__global__ __launch_bounds__(256) void mfmm_kernel(
    const uint32_t* __restrict__ Xp, const short* __restrict__ Whi,
    const short* __restrict__ Wlo, const float* __restrict__ bias,
    uint32_t* __restrict__ Hp, uint32_t* __restrict__ zp,
    float2* __restrict__ el2, float2* __restrict__ er2,
    const float* __restrict__ al, const float* __restrict__ ar, int n,
    const float* __restrict__ emb, const int* __restrict__ ids,
    const float* __restrict__ feat) {
  __shared__ short Ahi[64 * 136];
  __shared__ short Alo[64 * 136];
  const int t = threadIdx.x;
  const int nb = blockIdx.x * 64;

  // stage 64x128 inputs as split bf16 (hi/lo), 16B loads
  for (int idx = t; idx < 64 * 32; idx += 256) {
    int nl = idx >> 5, k4 = (idx & 31) << 2;
    int node = nb + nl;
    uint32_t h01 = 0, h23 = 0, l01 = 0, l23 = 0;
    if (node < n) {
      if (MODE == 1) {
        uint4 w = *(const uint4*)&Xp[(size_t)node * 128 + k4];
        h01 = (w.x >> 16) | (w.y & 0xffff0000u);
        l01 = (w.x & 0xffffu) | (w.y << 16);
        h23 = (w.z >> 16) | (w.w & 0xffff0000u);
        l23 = (w.z & 0xffffu) | (w.w << 16);
      } else {
        float4 v;
        if (k4 < 64) v = *(const float4*)&emb[(size_t)ids[node] * 64 + k4];
        else         v = *(const float4*)&feat[(size_t)node * 64 + (k4 - 64)];
        uint32_t a0 = bf16_rne(v.x), a1 = bf16_rne(v.y);
        uint32_t a2 = bf16_rne(v.z), a3 = bf16_rne(v.w);
        h01 = a0 | (a1 << 16);
        h23 = a2 | (a3 << 16);
        l01 = bf16_rne(v.x - __uint_as_float(a0 << 16)) |
              (bf16_rne(v.y - __uint_as_float(a1 << 16)) << 16);
        l23 = bf16_rne(v.z - __uint_as_float(a2 << 16)) |
              (bf16_rne(v.w - __uint_as_float(a3 << 16)) << 16);
      }
    }
    *(uint2*)&Ahi[nl * 136 + k4] = make_uint2(h01, h23);
    *(uint2*)&Alo[nl * 136 + k4] = make_uint2(l01, l23);
  }
  __syncthreads();

  const int lane = t & 63, wv = t >> 6;
  const int r16 = lane & 15, g = lane >> 4;
  const int arow = (wv * 16 + r16) * 136;

  f32x4 acc[8];
#pragma unroll
  for (int c = 0; c < 8; c++) acc[c] = (f32x4){0.f, 0.f, 0.f, 0.f};

#pragma unroll
  for (int q = 0; q < 4; q++) {
    int ka = q * 32 + g * 8;
    short8v ahi = *(const short8v*)&Ahi[arow + ka];
    short8v alo = *(const short8v*)&Alo[arow + ka];
#pragma unroll
    for (int c = 0; c < 8; c++) {
      short8v bhi = *(const short8v*)&Whi[(((q * 8 + c) * 64) + lane) * 8];
      short8v blo = *(const short8v*)&Wlo[(((q * 8 + c) * 64) + lane) * 8];
      acc[c] = __builtin_amdgcn_mfma_f32_16x16x32_bf16(ahi, bhi, acc[c], 0, 0, 0);
      acc[c] = __builtin_amdgcn_mfma_f32_16x16x32_bf16(ahi, blo, acc[c], 0, 0, 0);
      acc[c] = __builtin_amdgcn_mfma_f32_16x16x32_bf16(alo, bhi, acc[c], 0, 0, 0);
    }
  }

  const int node_base = nb + wv * 16;
  if (MODE == 0) {
#pragma unroll
    for (int c = 0; c < 8; c++) {
      int col = c * 16 + r16;
      float bv = bias[col];
#pragma unroll
      for (int r = 0; r < 4; r++) {
        int node = node_base + g * 4 + r;
        if (node < n) {
          float v = fmaxf(acc[c][r] + bv, 0.f);
          Hp[(size_t)node * 128 + col] = pack_hilo(v);
        }
      }
    }
  } else {
    float p0l[4] = {0, 0, 0, 0}, p1l[4] = {0, 0, 0, 0};
    float p0r[4] = {0, 0, 0, 0}, p1r[4] = {0, 0, 0, 0};
#pragma unroll
    for (int c = 0; c < 8; c++) {
      int col = c * 16 + r16;
      float av = al[col], rv = ar[col];
#pragma unroll
      for (int r = 0; r < 4; r++) {
        if (c < 4) { p0l[r] = fmaf(acc[c][r], av, p0l[r]); p0r[r] = fmaf(acc[c][r], rv, p0r[r]); }
        else       { p1l[r] = fmaf(acc[c][r], av, p1l[r]); p1r[r] = fmaf(acc[c][r], rv, p1r[r]); }
      }
    }
#pragma unroll
    for (int c = 0; c < 8; c++) {
#pragma unroll
      for (int r = 0; r < 4; r++) {
        float other = __shfl_xor(acc[c][r], 1, 64);
        int node = node_base + g * 4 + r;
        if (!(lane & 1) && node < n) {
          uint32_t w = bf16_rne(acc[c][r]) | (bf16_rne(other) << 16);
          zp[(size_t)node * 64 + c * 8 + (r16 >> 1)] = w;
        }
      }
    }
#pragma unroll
    for (int off = 1; off < 16; off <<= 1) {
#pragma unroll
      for (int r = 0; r < 4; r++) {
        p0l[r] += __shfl_xor(p0l[r], off, 64);
        p1l[r] += __shfl_xor(p1l[r], off, 64);
        p0r[r] += __shfl_xor(p0r[r], off, 64);
        p1r[r] += __shfl_xor(p1r[r], off, 64);
      }
    }
    if (r16 == 0) {
#pragma unroll
      for (int r = 0; r < 4; r++) {
        int node = node_base + g * 4 + r;
        if (node < n) {
          el2[node] = make_float2(p0l[r], p1l[r]);
          er2[node] = make_float2(p0r[r], p1r[r]);
        }
      }
    }
  }
}

// ---------------- GAT aggregation (wave per dst node) ----------------------
#define CAP 256
__global__ __launch_bounds__(256) void agg12_kernel(
    const uint32_t* __restrict__ zp, const float2* __restrict__ el2,
    const float2* __restrict__ er2, const int* __restrict__ row_start,
    const int* __restrict__ csr_src, const float* __restrict__ bias,
    uint32_t* __restrict__ Hp,
    const float* __restrict__ ow, const float* __restrict__ oal,
    const float* __restrict__ oar, float* __restrict__ z3,
    float* __restrict__ el3, float* __restrict__ er3, int n, int fuse_out) {
  __shared__ float ecf[4][2][CAP];
  __shared__ int sc[4][CAP];
  const int w = threadIdx.x >> 6, lane = threadIdx.x & 63;
  const int hl = lane >> 5, l32 = lane & 31;
  const int node = blockIdx.x * 4 + w;
  const bool valid = node < n;
  int rs = 0, deg = 0;
  float er_h = 0.f;
  if (valid) {
    rs = row_start[node];
    deg = row_start[node + 1] - rs;
    er_h = ((const float*)&er2[node])[hl];
  }
  const int cdeg = deg < CAP ? deg : CAP;

  // phase 1: full-wave head-split: half-wave h handles head h of 32 edges/iter
  float sp_h = 0.f;
  for (int i = l32; i < deg; i += 32) {
    int s = csr_src[rs + i];
    float lv = ((const float*)&el2[s])[hl];
    float x = __expf(lrelu(lv + er_h));
    if (i < CAP) {
      if (hl == 0) sc[w][i] = s;
      ecf[w][hl][i] = x;
    }
    sp_h += x;
  }
#pragma unroll
  for (int off = 16; off; off >>= 1) sp_h += __shfl_xor(sp_h, off, 64);
  __syncthreads();

  // phase 2: weighted z gather; 16/4/1 unroll, vector broadcast LDS reads
  const float* exh = ecf[w][hl];
  float ae = 0.f, ao = 0.f;
  int i = 0;
  for (; i + 16 <= cdeg; i += 16) {
    int s16[16];
    float x16[16];
#pragma unroll
    for (int q = 0; q < 4; q++) {
      int4 s4 = *(const int4*)&sc[w][i + q * 4];
      float4 x4 = *(const float4*)&exh[i + q * 4];
      s16[q * 4 + 0] = s4.x; s16[q * 4 + 1] = s4.y;
      s16[q * 4 + 2] = s4.z; s16[q * 4 + 3] = s4.w;
      x16[q * 4 + 0] = x4.x; x16[q * 4 + 1] = x4.y;
      x16[q * 4 + 2] = x4.z; x16[q * 4 + 3] = x4.w;
    }
    uint32_t zw[16];
#pragma unroll
    for (int u = 0; u < 16; u++) zw[u] = zp[(size_t)s16[u] * 64 + lane];
#pragma unroll
    for (int u = 0; u < 16; u++) {
      ae = fmaf(x16[u], __uint_as_float(zw[u] << 16), ae);
      ao = fmaf(x16[u], __uint_as_float(zw[u] & 0xffff0000u), ao);
    }
  }
  for (; i + 4 <= cdeg; i += 4) {
    int4 s4 = *(const int4*)&sc[w][i];
    float4 x4 = *(const float4*)&exh[i];
    uint32_t z0 = zp[(size_t)s4.x * 64 + lane];
    uint32_t z1 = zp[(size_t)s4.y * 64 + lane];
    uint32_t z2 = zp[(size_t)s4.z * 64 + lane];
    uint32_t z3v = zp[(size_t)s4.w * 64 + lane];
    ae = fmaf(x4.x, __uint_as_float(z0 << 16), ae);
    ao = fmaf(x4.x, __uint_as_float(z0 & 0xffff0000u), ao);
    ae = fmaf(x4.y, __uint_as_float(z1 << 16), ae);
    ao = fmaf(x4.y, __uint_as_float(z1 & 0xffff0000u), ao);
    ae = fmaf(x4.z, __uint_as_float(z2 << 16), ae);
    ao = fmaf(x4.z, __uint_as_float(z2 & 0xffff0000u), ao);
    ae = fmaf(x4.w, __uint_as_float(z3v << 16), ae);
    ao = fmaf(x4.w, __uint_as_float(z3v & 0xffff0000u), ao);
  }
  for (; i < cdeg; i++) {
    int s = sc[w][i];
    float x = exh[i];
    uint32_t zw = zp[(size_t)s * 64 + lane];
    ae = fmaf(x, __uint_as_float(zw << 16), ae);
    ao = fmaf(x, __uint_as_float(zw & 0xffff0000u), ao);
  }
  for (; i < deg; i++) {  // beyond-CAP tail (not hit for this graph)
    int s = csr_src[rs + i];
    float x = __expf(lrelu(((const float*)&el2[s])[hl] + er_h));
    uint32_t zw = zp[(size_t)s * 64 + lane];
    ae = fmaf(x, __uint_as_float(zw << 16), ae);
    ao = fmaf(x, __uint_as_float(zw & 0xffff0000u), ao);
  }

  if (valid) {
    float2 b2 = reinterpret_cast<const float2*>(bias)[lane];
    float oe, oo;
    if (deg == 0) { oe = b2.x; oo = b2.y; }
    else { oe = ae / sp_h + b2.x; oo = ao / sp_h + b2.y; }
    oe = fmaxf(oe, 0.f);
    oo = fmaxf(oo, 0.f);
    if (!fuse_out) {
      *(uint2*)&Hp[(size_t)node * 128 + 2 * lane] =
          make_uint2(pack_hilo(oe), pack_hilo(oo));
    } else {
      float2 w2 = reinterpret_cast<const float2*>(ow)[lane];
      float d = oe * w2.x + oo * w2.y;
#pragma unroll
      for (int off = 32; off; off >>= 1) d += __shfl_xor(d, off, 64);
      if (lane == 0) {
        z3[node] = d;
        el3[node] = d * oal[0];
        er3[node] = d * oar[0];
      }
    }
  }
}

// ---------------- output GAT layer: 32-lane group per node -----------------
__global__ __launch_bounds__(256) void agg3_kernel(
    const float* __restrict__ z3, const float* __restrict__ el3,
    const float* __restrict__ er3, const int* __restrict__ row_start,
    const int* __restrict__ csr_src, const float* __restrict__ b,
    float* __restrict__ out, int n) {
  int node = blockIdx.x * 8 + (threadIdx.x >> 5);
  int l32 = threadIdx.x & 31;
  if (node >= n) return;
  int rs = row_start[node];
  int deg = row_start[node + 1] - rs;
  float er = er3[node];
  float sp = 0.f, ap = 0.f;
  for (int i = l32; i < deg; i += 32) {
    int s = csr_src[rs + i];
    float ex = __expf(lrelu(el3[s] + er));
    sp += ex;
    ap = fmaf(ex, z3[s], ap);
  }
#pragma unroll
  for (int off = 16; off; off >>= 1) {
    sp += __shfl_xor(sp, off, 64);
    ap += __shfl_xor(ap, off, 64);
  }
  if (l32 == 0) out[node] = (deg == 0) ? b[0] : (ap / sp + b[0]);
}

// ---------------------------------------------------------------------------
extern "C" void kernel_launch(void* const* d_in, const int* in_sizes, int n_in,
                              void* d_out, int out_size, void* d_ws, size_t ws_size,
                              hipStream_t stream) {
  const float* feat     = (const float*)d_in[0];
  const int*   node_ids = (const int*)d_in[1];
  const int*   src      = (const int*)d_in[2];
  const int*   dst      = (const int*)d_in[3];
  const float* emb      = (const float*)d_in[4];
  const float* dense_w  = (const float*)d_in[5];
  const float* dense_b  = (const float*)d_in[6];
  const float* g1_w     = (const float*)d_in[7];
  const float* g1_al    = (const float*)d_in[8];
  const float* g1_ar    = (const float*)d_in[9];
  const float* g1_b     = (const float*)d_in[10];
  const float* g2_w     = (const float*)d_in[11];
  const float* g2_al    = (const float*)d_in[12];
  const float* g2_ar    = (const float*)d_in[13];
  const float* g2_b     = (const float*)d_in[14];
  const float* out_w    = (const float*)d_in[15];
  const float* out_al   = (const float*)d_in[16];
  const float* out_ar   = (const float*)d_in[17];
  const float* out_b    = (const float*)d_in[18];
  const int n = in_sizes[0] / 64;   // 50000
  const int e = in_sizes[2];        // 1600000

  const int ncb = (n + CBG - 1) / CBG;

  char* ws = (char*)d_ws;
  size_t off = 0;
  auto alloc = [&](size_t bytes) -> void* {
    void* p = ws + off;
    off += (bytes + 255) & ~(size_t)255;
    return p;
  };
  uint32_t* Hp       = (uint32_t*)alloc((size_t)n * 128 * 4);
  size_t zp_bytes    = (size_t)n * 64 * 4;
  size_t tmp_bytes   = (size_t)ncb * CAPC * 4;
  uint32_t* zp       = (uint32_t*)alloc(zp_bytes > tmp_bytes ? zp_bytes : tmp_bytes);
  uint32_t* tmp      = zp;
  float2*   el2      = (float2*)alloc((size_t)n * 8);
  float2*   er2      = (float2*)alloc((size_t)n * 8);
  float*    z3       = (float*)alloc((size_t)n * 4);
  float*    el3      = (float*)alloc((size_t)n * 4);
  float*    er3      = (float*)alloc((size_t)n * 4);
  int*      scount   = (int*)alloc((size_t)ncb * 4);
  int*      row_start= (int*)alloc((size_t)(n + 1) * 4);
  int*      csr_src  = (int*)alloc((size_t)e * 4);
  short*    Wd_hi    = (short*)alloc(2048 * 8 * 2);
  short*    Wd_lo    = (short*)alloc(2048 * 8 * 2);
  short*    W1_hi    = (short*)alloc(2048 * 8 * 2);
  short*    W1_lo    = (short*)alloc(2048 * 8 * 2);
  short*    W2_hi    = (short*)alloc(2048 * 8 * 2);
  short*    W2_lo    = (short*)alloc(2048 * 8 * 2);
  // fallback-only buffers
  int*      cnt      = (int*)alloc((size_t)n * 4);
  int*      cursor   = (int*)alloc((size_t)n * 4);
  const int nblk     = (n + 1023) / 1024;
  int*      bsum     = (int*)alloc((size_t)nblk * 4);

  // W split+swizzle (all 3 in one launch)
  wswz3_kernel<<<24, 256, 0, stream>>>(dense_w, g1_w, g2_w,
                                       Wd_hi, Wd_lo, W1_hi, W1_lo, W2_hi, W2_lo);

  // CSR build
  if (n < 65536) {
    hipMemsetAsync(scount, 0, (size_t)ncb * 4, stream);
    const int natile = (e + TILE - 1) / TILE;
    bucketA_kernel<<<natile, 256, 0, stream>>>(src, dst, scount, tmp, e, ncb);
    bucketB_kernel<<<ncb, 256, 0, stream>>>(tmp, scount, row_start, csr_src,
                                            n, ncb, e);
  } else {
    hipMemsetAsync(cnt, 0, (size_t)n * 4, stream);
    hipMemsetAsync(cursor, 0, (size_t)n * 4, stream);
    hist_kernel<<<2048, 256, 0, stream>>>(dst, cnt, e);
    scan1_kernel<<<nblk, 1024, 0, stream>>>(cnt, row_start, bsum, n);
    scan2_kernel<<<1, 64, 0, stream>>>(bsum, nblk);
    scan3_kernel<<<(n + 255) / 256, 256, 0, stream>>>(row_start, bsum, n, e);
    scatter_kernel<<<2048, 256, 0, stream>>>(src, dst, row_start, cursor, csr_src, e);
  }

  const int mmgrid = (n + 63) / 64;
  const int ngrid4 = (n + 3) / 4;
  const int ngrid8 = (n + 7) / 8;

  // dense: Hp = pack(relu(concat @ dense_w + dense_b))
  mfmm_kernel<0><<<mmgrid, 256, 0, stream>>>(nullptr, Wd_hi, Wd_lo, dense_b,
                                             Hp, nullptr, nullptr, nullptr,
                                             nullptr, nullptr, n, emb, node_ids, feat);
  // GAT layer 1
  mfmm_kernel<1><<<mmgrid, 256, 0, stream>>>(Hp, W1_hi, W1_lo, nullptr,
                                             nullptr, zp, el2, er2,
                                             g1_al, g1_ar, n, nullptr, nullptr, nullptr);
  agg12_kernel<<<ngrid4, 256, 0, stream>>>(zp, el2, er2, row_start, csr_src, g1_b, Hp,
                                           nullptr, nullptr, nullptr, nullptr, nullptr,
                                           nullptr, n, 0);
  // GAT layer 2 (+ fused output-layer z3/el3/er3)
  mfmm_kernel<1><<<mmgrid, 256, 0, stream>>>(Hp, W2_hi, W2_lo, nullptr,
                                             nullptr, zp, el2, er2,
                                             g2_al, g2_ar, n, nullptr, nullptr, nullptr);
  agg12_kernel<<<ngrid4, 256, 0, stream>>>(zp, el2, er2, row_start, csr_src, g2_b, nullptr,
                                           out_w, out_al, out_ar, z3, el3, er3, n, 1);
  // output GAT layer aggregation
  agg3_kernel<<<ngrid8, 256, 0, stream>>>(z3, el3, er3, row_start, csr_src, out_b,
                                          (float*)d_out, n);
}

// Round 8
// 240.303 us; speedup vs baseline: 1.1064x; 1.1064x over previous
//
#include <hip/hip_runtime.h>
#include <cfloat>
#include <cmath>

// ---------------------------------------------------------------------------
// UncertaintyGAT. Round-8: revert agg12 to the r6 operating point (8-unroll,
// 32 VGPR, full-wave float2 phase-1) -- r7's 16-unroll+head-split cost 24 µs
// via register pressure (44 VGPR, occ 67->44%). Keep r7's fused bucketB scan,
// single wswz3 launch, 32-lane agg3. bucketA TILE 8192->4096 (196->391 blocks,
// 35->19 KB LDS) to fill all 256 CUs during CSR build.
// ---------------------------------------------------------------------------

#define CBG 256
#define CAPC 12288
#define TILE 4096
#define BIMG 10240

typedef __attribute__((ext_vector_type(8))) short short8v;
typedef __attribute__((ext_vector_type(4))) float f32x4;

__device__ __forceinline__ float lrelu(float x) { return x > 0.f ? x : 0.2f * x; }

__device__ __forceinline__ uint32_t bf16_rne(float f) {
  uint32_t u = __float_as_uint(f);
  return (u + 0x7fffu + ((u >> 16) & 1u)) >> 16;
}
__device__ __forceinline__ uint32_t pack_hilo(float v) {
  uint32_t h = bf16_rne(v);
  float r = v - __uint_as_float(h << 16);
  return (h << 16) | bf16_rne(r);
}

// ---------------- CSR build (n < 65536 path) ----------------
__global__ __launch_bounds__(256) void bucketA_kernel(
    const int* __restrict__ src, const int* __restrict__ dst,
    int* __restrict__ scount, uint32_t* __restrict__ tmp, int e, int ncb) {
  __shared__ int cnt[256];
  __shared__ int lscan[256];
  __shared__ int gbase[256];
  __shared__ uint32_t image[TILE];
  const int t = threadIdx.x;
  const int e0 = blockIdx.x * TILE;
  const int ne = min(TILE, e - e0);

  for (int i = t; i < 256; i += 256) cnt[i] = 0;
  __syncthreads();
  for (int i = t; i < ne; i += 256) atomicAdd(&cnt[dst[e0 + i] >> 8], 1);
  __syncthreads();
  if (t < 64) {
    int carry = 0;
    for (int base = 0; base < ncb; base += 64) {
      int idx = base + t;
      int c = (idx < ncb) ? cnt[idx] : 0;
      int v = c;
#pragma unroll
      for (int off = 1; off < 64; off <<= 1) {
        int u = __shfl_up(v, off, 64);
        if (t >= off) v += u;
      }
      if (idx < ncb) lscan[idx] = carry + v - c;
      carry += __shfl(v, 63, 64);
    }
  }
  __syncthreads();
  for (int b = t; b < ncb; b += 256)
    gbase[b] = (cnt[b] > 0) ? atomicAdd(&scount[b], cnt[b]) : 0;
  __syncthreads();
  for (int b = t; b < ncb; b += 256) cnt[b] = 0;
  __syncthreads();
  for (int i = t; i < ne; i += 256) {
    int d = dst[e0 + i], s = src[e0 + i];
    int b = d >> 8;
    int r = atomicAdd(&cnt[b], 1);
    image[lscan[b] + r] =
        (uint32_t)s | ((uint32_t)(d & 255) << 16) | ((uint32_t)b << 24);
  }
  __syncthreads();
  for (int j = t; j < ne; j += 256) {
    uint32_t w = image[j];
    int b = w >> 24;
    int pos = gbase[b] + (j - lscan[b]);
    if (pos < CAPC) tmp[(size_t)b * CAPC + pos] = w & 0xFFFFFFu;
  }
}

// bucketB with inline base computation (masked sum over scount[0..b))
__global__ __launch_bounds__(256) void bucketB_kernel(
    const uint32_t* __restrict__ tmp, const int* __restrict__ scount,
    int* __restrict__ row_start, int* __restrict__ csr_src, int n, int ncb, int e) {
  __shared__ int cnt[256];
  __shared__ int cur[256];
  __shared__ int wsum[4];
  __shared__ int s_base;
  __shared__ uint32_t image[BIMG];
  const int b = blockIdx.x, t = threadIdx.x, lane = t & 63, wid = t >> 6;

  if (t < 64) {
    int part = 0;
    for (int idx = lane; idx < b; idx += 64) part += scount[idx];
#pragma unroll
    for (int off = 32; off; off >>= 1) part += __shfl_xor(part, off, 64);
    if (lane == 0) s_base = part;
  }
  cnt[t] = 0;
  __syncthreads();
  const int total = min(scount[b], CAPC);
  const int base = s_base;
  const uint32_t* strm = tmp + (size_t)b * CAPC;

  for (int i = t; i < total; i += 256) atomicAdd(&cnt[(strm[i] >> 16) & 255], 1);
  __syncthreads();
  int c = cnt[t], v = c;
#pragma unroll
  for (int off = 1; off < 64; off <<= 1) {
    int u = __shfl_up(v, off, 64);
    if (lane >= off) v += u;
  }
  if (lane == 63) wsum[wid] = v;
  __syncthreads();
  if (t == 0) {
    int acc = 0;
#pragma unroll
    for (int w = 0; w < 4; w++) { int x = wsum[w]; wsum[w] = acc; acc += x; }
  }
  __syncthreads();
  int ex = wsum[wid] + v - c;
  cur[t] = ex;
  int d = b * CBG + t;
  if (d < n) row_start[d] = base + ex;
  if (b == 0 && t == 0) row_start[n] = e;
  __syncthreads();
  for (int i = t; i < total; i += 256) {
    uint32_t w = strm[i];
    int dl = (w >> 16) & 255;
    int pos = atomicAdd(&cur[dl], 1);
    if (pos < BIMG) image[pos] = w & 0xFFFFu;
    else csr_src[base + pos] = (int)(w & 0xFFFFu);
  }
  __syncthreads();
  const int lim = total < BIMG ? total : BIMG;
  for (int j = t; j < lim; j += 256) csr_src[base + j] = (int)image[j];
}

// ---------------- fallback path (n >= 65536) ----------------
__global__ void hist_kernel(const int* __restrict__ dst, int* __restrict__ cnt, int e) {
  for (int i = blockIdx.x * blockDim.x + threadIdx.x; i < e; i += gridDim.x * blockDim.x)
    atomicAdd(&cnt[dst[i]], 1);
}
__global__ void scatter_kernel(const int* __restrict__ src, const int* __restrict__ dst,
                               const int* __restrict__ row_start, int* __restrict__ cursor,
                               int* __restrict__ csr_src, int e) {
  for (int i = blockIdx.x * blockDim.x + threadIdx.x; i < e; i += gridDim.x * blockDim.x) {
    int d = dst[i];
    int pos = atomicAdd(&cursor[d], 1);
    csr_src[row_start[d] + pos] = src[i];
  }
}
__global__ __launch_bounds__(1024) void scan1_kernel(const int* __restrict__ cnt,
                                                     int* __restrict__ row_start,
                                                     int* __restrict__ bsum, int n) {
  __shared__ int wsum[16];
  const int t = threadIdx.x, lane = t & 63, wid = t >> 6;
  int i = blockIdx.x * 1024 + t;
  int c = (i < n) ? cnt[i] : 0;
  int v = c;
#pragma unroll
  for (int off = 1; off < 64; off <<= 1) {
    int u = __shfl_up(v, off, 64);
    if (lane >= off) v += u;
  }
  if (lane == 63) wsum[wid] = v;
  __syncthreads();
  if (t == 0) {
    int acc = 0;
#pragma unroll
    for (int w = 0; w < 16; w++) { int x = wsum[w]; wsum[w] = acc; acc += x; }
    bsum[blockIdx.x] = acc;
  }
  __syncthreads();
  if (i < n) row_start[i] = wsum[wid] + v - c;
}
__global__ __launch_bounds__(64) void scan2_kernel(int* __restrict__ bsum, int nb) {
  const int lane = threadIdx.x;
  int carry = 0;
  for (int base = 0; base < nb; base += 64) {
    int idx = base + lane;
    int c = (idx < nb) ? bsum[idx] : 0;
    int v = c;
#pragma unroll
    for (int off = 1; off < 64; off <<= 1) {
      int u = __shfl_up(v, off, 64);
      if (lane >= off) v += u;
    }
    if (idx < nb) bsum[idx] = carry + v - c;
    carry += __shfl(v, 63, 64);
  }
}
__global__ void scan3_kernel(int* __restrict__ row_start, const int* __restrict__ bsum,
                             int n, int e) {
  int i = blockIdx.x * blockDim.x + threadIdx.x;
  if (i < n) row_start[i] += bsum[i >> 10];
  if (i == 0) row_start[n] = e;
}

// ---------------- W pre-split+swizzle, all 3 weights in one launch ---------
__global__ __launch_bounds__(256) void wswz3_kernel(
    const float* __restrict__ W0, const float* __restrict__ W1,
    const float* __restrict__ W2, short* __restrict__ Whi0,
    short* __restrict__ Wlo0, short* __restrict__ Whi1, short* __restrict__ Wlo1,
    short* __restrict__ Whi2, short* __restrict__ Wlo2) {
  int which = blockIdx.x >> 3;
  const float* W = which == 0 ? W0 : (which == 1 ? W1 : W2);
  short* Whi = which == 0 ? Whi0 : (which == 1 ? Whi1 : Whi2);
  short* Wlo = which == 0 ? Wlo0 : (which == 1 ? Wlo1 : Wlo2);
  int fid = (blockIdx.x & 7) * 256 + threadIdx.x;  // 0..2047
  int lane = fid & 63;
  int cq = fid >> 6;
  int q = cq >> 3, c = cq & 7;
  int col = c * 16 + (lane & 15);
  int k0 = q * 32 + (lane >> 4) * 8;
#pragma unroll
  for (int j = 0; j < 8; j++) {
    float v = W[(k0 + j) * 128 + col];
    uint32_t h = bf16_rne(v);
    float r = v - __uint_as_float(h << 16);
    Whi[fid * 8 + j] = (short)h;
    Wlo[fid * 8 + j] = (short)bf16_rne(r);
  }
}

// ---------------- MFMA GEMM: 64 nodes/block, N=128, K=128 ------------------
template <int MODE>
__global__ __launch_bounds__(256) void mfmm_kernel(
    const uint32_t* __restrict__ Xp, const short* __restrict__ Whi,
    const short* __restrict__ Wlo, const float* __restrict__ bias,
    uint32_t* __restrict__ Hp, uint32_t* __restrict__ zp,
    float2* __restrict__ el2, float2* __restrict__ er2,
    const float* __restrict__ al, const float* __restrict__ ar, int n,
    const float* __restrict__ emb, const int* __restrict__ ids,
    const float* __restrict__ feat) {
  __shared__ short Ahi[64 * 136];
  __shared__ short Alo[64 * 136];
  const int t = threadIdx.x;
  const int nb = blockIdx.x * 64;

  for (int idx = t; idx < 64 * 32; idx += 256) {
    int nl = idx >> 5, k4 = (idx & 31) << 2;
    int node = nb + nl;
    uint32_t h01 = 0, h23 = 0, l01 = 0, l23 = 0;
    if (node < n) {
      if (MODE == 1) {
        uint4 w = *(const uint4*)&Xp[(size_t)node * 128 + k4];
        h01 = (w.x >> 16) | (w.y & 0xffff0000u);
        l01 = (w.x & 0xffffu) | (w.y << 16);
        h23 = (w.z >> 16) | (w.w & 0xffff0000u);
        l23 = (w.z & 0xffffu) | (w.w << 16);
      } else {
        float4 v;
        if (k4 < 64) v = *(const float4*)&emb[(size_t)ids[node] * 64 + k4];
        else         v = *(const float4*)&feat[(size_t)node * 64 + (k4 - 64)];
        uint32_t a0 = bf16_rne(v.x), a1 = bf16_rne(v.y);
        uint32_t a2 = bf16_rne(v.z), a3 = bf16_rne(v.w);
        h01 = a0 | (a1 << 16);
        h23 = a2 | (a3 << 16);
        l01 = bf16_rne(v.x - __uint_as_float(a0 << 16)) |
              (bf16_rne(v.y - __uint_as_float(a1 << 16)) << 16);
        l23 = bf16_rne(v.z - __uint_as_float(a2 << 16)) |
              (bf16_rne(v.w - __uint_as_float(a3 << 16)) << 16);
      }
    }
    *(uint2*)&Ahi[nl * 136 + k4] = make_uint2(h01, h23);
    *(uint2*)&Alo[nl * 136 + k4] = make_uint2(l01, l23);
  }
  __syncthreads();

  const int lane = t & 63, wv = t >> 6;
  const int r16 = lane & 15, g = lane >> 4;
  const int arow = (wv * 16 + r16) * 136;

  f32x4 acc[8];
#pragma unroll
  for (int c = 0; c < 8; c++) acc[c] = (f32x4){0.f, 0.f, 0.f, 0.f};

#pragma unroll
  for (int q = 0; q < 4; q++) {
    int ka = q * 32 + g * 8;
    short8v ahi = *(const short8v*)&Ahi[arow + ka];
    short8v alo = *(const short8v*)&Alo[arow + ka];
#pragma unroll
    for (int c = 0; c < 8; c++) {
      short8v bhi = *(const short8v*)&Whi[(((q * 8 + c) * 64) + lane) * 8];
      short8v blo = *(const short8v*)&Wlo[(((q * 8 + c) * 64) + lane) * 8];
      acc[c] = __builtin_amdgcn_mfma_f32_16x16x32_bf16(ahi, bhi, acc[c], 0, 0, 0);
      acc[c] = __builtin_amdgcn_mfma_f32_16x16x32_bf16(ahi, blo, acc[c], 0, 0, 0);
      acc[c] = __builtin_amdgcn_mfma_f32_16x16x32_bf16(alo, bhi, acc[c], 0, 0, 0);
    }
  }

  const int node_base = nb + wv * 16;
  if (MODE == 0) {
#pragma unroll
    for (int c = 0; c < 8; c++) {
      int col = c * 16 + r16;
      float bv = bias[col];
#pragma unroll
      for (int r = 0; r < 4; r++) {
        int node = node_base + g * 4 + r;
        if (node < n) {
          float v = fmaxf(acc[c][r] + bv, 0.f);
          Hp[(size_t)node * 128 + col] = pack_hilo(v);
        }
      }
    }
  } else {
    float p0l[4] = {0, 0, 0, 0}, p1l[4] = {0, 0, 0, 0};
    float p0r[4] = {0, 0, 0, 0}, p1r[4] = {0, 0, 0, 0};
#pragma unroll
    for (int c = 0; c < 8; c++) {
      int col = c * 16 + r16;
      float av = al[col], rv = ar[col];
#pragma unroll
      for (int r = 0; r < 4; r++) {
        if (c < 4) { p0l[r] = fmaf(acc[c][r], av, p0l[r]); p0r[r] = fmaf(acc[c][r], rv, p0r[r]); }
        else       { p1l[r] = fmaf(acc[c][r], av, p1l[r]); p1r[r] = fmaf(acc[c][r], rv, p1r[r]); }
      }
    }
#pragma unroll
    for (int c = 0; c < 8; c++) {
#pragma unroll
      for (int r = 0; r < 4; r++) {
        float other = __shfl_xor(acc[c][r], 1, 64);
        int node = node_base + g * 4 + r;
        if (!(lane & 1) && node < n) {
          uint32_t w = bf16_rne(acc[c][r]) | (bf16_rne(other) << 16);
          zp[(size_t)node * 64 + c * 8 + (r16 >> 1)] = w;
        }
      }
    }
#pragma unroll
    for (int off = 1; off < 16; off <<= 1) {
#pragma unroll
      for (int r = 0; r < 4; r++) {
        p0l[r] += __shfl_xor(p0l[r], off, 64);
        p1l[r] += __shfl_xor(p1l[r], off, 64);
        p0r[r] += __shfl_xor(p0r[r], off, 64);
        p1r[r] += __shfl_xor(p1r[r], off, 64);
      }
    }
    if (r16 == 0) {
#pragma unroll
      for (int r = 0; r < 4; r++) {
        int node = node_base + g * 4 + r;
        if (node < n) {
          el2[node] = make_float2(p0l[r], p1l[r]);
          er2[node] = make_float2(p0r[r], p1r[r]);
        }
      }
    }
  }
}

// ---------------- GAT aggregation (wave per dst node) -- r6 structure ------
#define CAP 256
__global__ __launch_bounds__(256) void agg12_kernel(
    const uint32_t* __restrict__ zp, const float2* __restrict__ el2,
    const float2* __restrict__ er2, const int* __restrict__ row_start,
    const int* __restrict__ csr_src, const float* __restrict__ bias,
    uint32_t* __restrict__ Hp,
    const float* __restrict__ ow, const float* __restrict__ oal,
    const float* __restrict__ oar, float* __restrict__ z3,
    float* __restrict__ el3, float* __restrict__ er3, int n, int fuse_out) {
  __shared__ float2 ec[4][CAP];
  __shared__ int sc[4][CAP];
  const int w = threadIdx.x >> 6, lane = threadIdx.x & 63;
  const int node = blockIdx.x * 4 + w;
  const bool valid = node < n;
  int rs = 0, deg = 0;
  float er0 = 0.f, er1 = 0.f;
  if (valid) {
    rs = row_start[node];
    deg = row_start[node + 1] - rs;
    float2 e2 = er2[node];
    er0 = e2.x; er1 = e2.y;
  }
  const int cdeg = deg < CAP ? deg : CAP;

  float sp0 = 0.f, sp1 = 0.f;
  for (int i = lane; i < deg; i += 64) {
    int s = csr_src[rs + i];
    float2 l = el2[s];
    float x0 = __expf(lrelu(l.x + er0));
    float x1 = __expf(lrelu(l.y + er1));
    if (i < CAP) { sc[w][i] = s; ec[w][i] = make_float2(x0, x1); }
    sp0 += x0; sp1 += x1;
  }
#pragma unroll
  for (int off = 32; off; off >>= 1) {
    sp0 += __shfl_xor(sp0, off, 64);
    sp1 += __shfl_xor(sp1, off, 64);
  }
  __syncthreads();

  float ae = 0.f, ao = 0.f;
  int i = 0;
  for (; i + 8 <= cdeg; i += 8) {
    uint32_t zw[8];
    float xh[8];
#pragma unroll
    for (int u = 0; u < 8; u++) {
      int s = sc[w][i + u];
      float2 ex = ec[w][i + u];
      xh[u] = (lane < 32) ? ex.x : ex.y;
      zw[u] = zp[(size_t)s * 64 + lane];
    }
#pragma unroll
    for (int u = 0; u < 8; u++) {
      ae = fmaf(xh[u], __uint_as_float(zw[u] << 16), ae);
      ao = fmaf(xh[u], __uint_as_float(zw[u] & 0xffff0000u), ao);
    }
  }
  for (; i < cdeg; i++) {
    int s = sc[w][i];
    float2 ex = ec[w][i];
    float x = (lane < 32) ? ex.x : ex.y;
    uint32_t zw = zp[(size_t)s * 64 + lane];
    ae = fmaf(x, __uint_as_float(zw << 16), ae);
    ao = fmaf(x, __uint_as_float(zw & 0xffff0000u), ao);
  }
  for (; i < deg; i++) {
    int s = csr_src[rs + i];
    float2 l = el2[s];
    float x0 = __expf(lrelu(l.x + er0));
    float x1 = __expf(lrelu(l.y + er1));
    float x = (lane < 32) ? x0 : x1;
    uint32_t zw = zp[(size_t)s * 64 + lane];
    ae = fmaf(x, __uint_as_float(zw << 16), ae);
    ao = fmaf(x, __uint_as_float(zw & 0xffff0000u), ao);
  }

  if (valid) {
    float sp = (lane < 32) ? sp0 : sp1;
    float2 b2 = reinterpret_cast<const float2*>(bias)[lane];
    float oe, oo;
    if (deg == 0) { oe = b2.x; oo = b2.y; }
    else { oe = ae / sp + b2.x; oo = ao / sp + b2.y; }
    oe = fmaxf(oe, 0.f);
    oo = fmaxf(oo, 0.f);
    if (!fuse_out) {
      *(uint2*)&Hp[(size_t)node * 128 + 2 * lane] =
          make_uint2(pack_hilo(oe), pack_hilo(oo));
    } else {
      float2 w2 = reinterpret_cast<const float2*>(ow)[lane];
      float d = oe * w2.x + oo * w2.y;
#pragma unroll
      for (int off = 32; off; off >>= 1) d += __shfl_xor(d, off, 64);
      if (lane == 0) {
        z3[node] = d;
        el3[node] = d * oal[0];
        er3[node] = d * oar[0];
      }
    }
  }
}

// ---------------- output GAT layer: 32-lane group per node -----------------
__global__ __launch_bounds__(256) void agg3_kernel(
    const float* __restrict__ z3, const float* __restrict__ el3,
    const float* __restrict__ er3, const int* __restrict__ row_start,
    const int* __restrict__ csr_src, const float* __restrict__ b,
    float* __restrict__ out, int n) {
  int node = blockIdx.x * 8 + (threadIdx.x >> 5);
  int l32 = threadIdx.x & 31;
  if (node >= n) return;
  int rs = row_start[node];
  int deg = row_start[node + 1] - rs;
  float er = er3[node];
  float sp = 0.f, ap = 0.f;
  for (int i = l32; i < deg; i += 32) {
    int s = csr_src[rs + i];
    float ex = __expf(lrelu(el3[s] + er));
    sp += ex;
    ap = fmaf(ex, z3[s], ap);
  }
#pragma unroll
  for (int off = 16; off; off >>= 1) {
    sp += __shfl_xor(sp, off, 64);
    ap += __shfl_xor(ap, off, 64);
  }
  if (l32 == 0) out[node] = (deg == 0) ? b[0] : (ap / sp + b[0]);
}

// ---------------------------------------------------------------------------
extern "C" void kernel_launch(void* const* d_in, const int* in_sizes, int n_in,
                              void* d_out, int out_size, void* d_ws, size_t ws_size,
                              hipStream_t stream) {
  const float* feat     = (const float*)d_in[0];
  const int*   node_ids = (const int*)d_in[1];
  const int*   src      = (const int*)d_in[2];
  const int*   dst      = (const int*)d_in[3];
  const float* emb      = (const float*)d_in[4];
  const float* dense_w  = (const float*)d_in[5];
  const float* dense_b  = (const float*)d_in[6];
  const float* g1_w     = (const float*)d_in[7];
  const float* g1_al    = (const float*)d_in[8];
  const float* g1_ar    = (const float*)d_in[9];
  const float* g1_b     = (const float*)d_in[10];
  const float* g2_w     = (const float*)d_in[11];
  const float* g2_al    = (const float*)d_in[12];
  const float* g2_ar    = (const float*)d_in[13];
  const float* g2_b     = (const float*)d_in[14];
  const float* out_w    = (const float*)d_in[15];
  const float* out_al   = (const float*)d_in[16];
  const float* out_ar   = (const float*)d_in[17];
  const float* out_b    = (const float*)d_in[18];
  const int n = in_sizes[0] / 64;   // 50000
  const int e = in_sizes[2];        // 1600000

  const int ncb = (n + CBG - 1) / CBG;

  char* ws = (char*)d_ws;
  size_t off = 0;
  auto alloc = [&](size_t bytes) -> void* {
    void* p = ws + off;
    off += (bytes + 255) & ~(size_t)255;
    return p;
  };
  uint32_t* Hp       = (uint32_t*)alloc((size_t)n * 128 * 4);
  size_t zp_bytes    = (size_t)n * 64 * 4;
  size_t tmp_bytes   = (size_t)ncb * CAPC * 4;
  uint32_t* zp       = (uint32_t*)alloc(zp_bytes > tmp_bytes ? zp_bytes : tmp_bytes);
  uint32_t* tmp      = zp;
  float2*   el2      = (float2*)alloc((size_t)n * 8);
  float2*   er2      = (float2*)alloc((size_t)n * 8);
  float*    z3       = (float*)alloc((size_t)n * 4);
  float*    el3      = (float*)alloc((size_t)n * 4);
  float*    er3      = (float*)alloc((size_t)n * 4);
  int*      scount   = (int*)alloc((size_t)ncb * 4);
  int*      row_start= (int*)alloc((size_t)(n + 1) * 4);
  int*      csr_src  = (int*)alloc((size_t)e * 4);
  short*    Wd_hi    = (short*)alloc(2048 * 8 * 2);
  short*    Wd_lo    = (short*)alloc(2048 * 8 * 2);
  short*    W1_hi    = (short*)alloc(2048 * 8 * 2);
  short*    W1_lo    = (short*)alloc(2048 * 8 * 2);
  short*    W2_hi    = (short*)alloc(2048 * 8 * 2);
  short*    W2_lo    = (short*)alloc(2048 * 8 * 2);
  // fallback-only buffers
  int*      cnt      = (int*)alloc((size_t)n * 4);
  int*      cursor   = (int*)alloc((size_t)n * 4);
  const int nblk     = (n + 1023) / 1024;
  int*      bsum     = (int*)alloc((size_t)nblk * 4);

  // W split+swizzle (all 3 in one launch)
  wswz3_kernel<<<24, 256, 0, stream>>>(dense_w, g1_w, g2_w,
                                       Wd_hi, Wd_lo, W1_hi, W1_lo, W2_hi, W2_lo);

  // CSR build
  if (n < 65536) {
    hipMemsetAsync(scount, 0, (size_t)ncb * 4, stream);
    const int natile = (e + TILE - 1) / TILE;
    bucketA_kernel<<<natile, 256, 0, stream>>>(src, dst, scount, tmp, e, ncb);
    bucketB_kernel<<<ncb, 256, 0, stream>>>(tmp, scount, row_start, csr_src,
                                            n, ncb, e);
  } else {
    hipMemsetAsync(cnt, 0, (size_t)n * 4, stream);
    hipMemsetAsync(cursor, 0, (size_t)n * 4, stream);
    hist_kernel<<<2048, 256, 0, stream>>>(dst, cnt, e);
    scan1_kernel<<<nblk, 1024, 0, stream>>>(cnt, row_start, bsum, n);
    scan2_kernel<<<1, 64, 0, stream>>>(bsum, nblk);
    scan3_kernel<<<(n + 255) / 256, 256, 0, stream>>>(row_start, bsum, n, e);
    scatter_kernel<<<2048, 256, 0, stream>>>(src, dst, row_start, cursor, csr_src, e);
  }

  const int mmgrid = (n + 63) / 64;
  const int ngrid4 = (n + 3) / 4;
  const int ngrid8 = (n + 7) / 8;

  // dense: Hp = pack(relu(concat @ dense_w + dense_b))
  mfmm_kernel<0><<<mmgrid, 256, 0, stream>>>(nullptr, Wd_hi, Wd_lo, dense_b,
                                             Hp, nullptr, nullptr, nullptr,
                                             nullptr, nullptr, n, emb, node_ids, feat);
  // GAT layer 1
  mfmm_kernel<1><<<mmgrid, 256, 0, stream>>>(Hp, W1_hi, W1_lo, nullptr,
                                             nullptr, zp, el2, er2,
                                             g1_al, g1_ar, n, nullptr, nullptr, nullptr);
  agg12_kernel<<<ngrid4, 256, 0, stream>>>(zp, el2, er2, row_start, csr_src, g1_b, Hp,
                                           nullptr, nullptr, nullptr, nullptr, nullptr,
                                           nullptr, n, 0);
  // GAT layer 2 (+ fused output-layer z3/el3/er3)
  mfmm_kernel<1><<<mmgrid, 256, 0, stream>>>(Hp, W2_hi, W2_lo, nullptr,
                                             nullptr, zp, el2, er2,
                                             g2_al, g2_ar, n, nullptr, nullptr, nullptr);
  agg12_kernel<<<ngrid4, 256, 0, stream>>>(zp, el2, er2, row_start, csr_src, g2_b, nullptr,
                                           out_w, out_al, out_ar, z3, el3, er3, n, 1);
  // output GAT layer aggregation
  agg3_kernel<<<ngrid8, 256, 0, stream>>>(z3, el3, er3, row_start, csr_src, out_b,
                                          (float*)d_out, n);
}

// Round 9
// 237.765 us; speedup vs baseline: 1.1182x; 1.0107x over previous
//
#include <hip/hip_runtime.h>
#include <cfloat>
#include <cmath>

// ---------------------------------------------------------------------------
// UncertaintyGAT. Round-9: fill the machine during CSR build + cut launches.
//  - bucketA TILE 2048 (782 blocks, ~3/CU resident; was 391 at 1.5/CU)
//  - bucketB fused into the dense-GEMM launch (independent work, overlapped;
//    43KB LDS union, block-range dispatch)
//  - scount zeroing folded into the weight-swizzle prep kernel
//  8 dispatches total (was 11). agg12 kept at the r6/r8 operating point
//  (8-unroll, 32 VGPR -- r7 proved deeper unroll regresses via occupancy).
// ---------------------------------------------------------------------------

#define CBG 256
#define CAPC 12288
#define TILE 2048
#define BIMG 10240

typedef __attribute__((ext_vector_type(8))) short short8v;
typedef __attribute__((ext_vector_type(4))) float f32x4;

__device__ __forceinline__ float lrelu(float x) { return x > 0.f ? x : 0.2f * x; }

__device__ __forceinline__ uint32_t bf16_rne(float f) {
  uint32_t u = __float_as_uint(f);
  return (u + 0x7fffu + ((u >> 16) & 1u)) >> 16;
}
__device__ __forceinline__ uint32_t pack_hilo(float v) {
  uint32_t h = bf16_rne(v);
  float r = v - __uint_as_float(h << 16);
  return (h << 16) | bf16_rne(r);
}

// ---------------- prep: W split+swizzle (blocks 0..23) + scount zero -------
__global__ __launch_bounds__(256) void prep_kernel(
    const float* __restrict__ W0, const float* __restrict__ W1,
    const float* __restrict__ W2, short* __restrict__ Whi0,
    short* __restrict__ Wlo0, short* __restrict__ Whi1, short* __restrict__ Wlo1,
    short* __restrict__ Whi2, short* __restrict__ Wlo2,
    int* __restrict__ scount, int ncb) {
  if (blockIdx.x >= 24) {
    for (int i = threadIdx.x; i < ncb; i += 256) scount[i] = 0;
    return;
  }
  int which = blockIdx.x >> 3;
  const float* W = which == 0 ? W0 : (which == 1 ? W1 : W2);
  short* Whi = which == 0 ? Whi0 : (which == 1 ? Whi1 : Whi2);
  short* Wlo = which == 0 ? Wlo0 : (which == 1 ? Wlo1 : Wlo2);
  int fid = (blockIdx.x & 7) * 256 + threadIdx.x;  // 0..2047
  int lane = fid & 63;
  int cq = fid >> 6;
  int q = cq >> 3, c = cq & 7;
  int col = c * 16 + (lane & 15);
  int k0 = q * 32 + (lane >> 4) * 8;
#pragma unroll
  for (int j = 0; j < 8; j++) {
    float v = W[(k0 + j) * 128 + col];
    uint32_t h = bf16_rne(v);
    float r = v - __uint_as_float(h << 16);
    Whi[fid * 8 + j] = (short)h;
    Wlo[fid * 8 + j] = (short)bf16_rne(r);
  }
}

// ---------------- CSR build (n < 65536 path) ----------------
__global__ __launch_bounds__(256) void bucketA_kernel(
    const int* __restrict__ src, const int* __restrict__ dst,
    int* __restrict__ scount, uint32_t* __restrict__ tmp, int e, int ncb) {
  __shared__ int cnt[256];
  __shared__ int lscan[256];
  __shared__ int gbase[256];
  __shared__ uint32_t image[TILE];
  const int t = threadIdx.x;
  const int e0 = blockIdx.x * TILE;
  const int ne = min(TILE, e - e0);

  for (int i = t; i < 256; i += 256) cnt[i] = 0;
  __syncthreads();
  for (int i = t; i < ne; i += 256) atomicAdd(&cnt[dst[e0 + i] >> 8], 1);
  __syncthreads();
  if (t < 64) {
    int carry = 0;
    for (int base = 0; base < ncb; base += 64) {
      int idx = base + t;
      int c = (idx < ncb) ? cnt[idx] : 0;
      int v = c;
#pragma unroll
      for (int off = 1; off < 64; off <<= 1) {
        int u = __shfl_up(v, off, 64);
        if (t >= off) v += u;
      }
      if (idx < ncb) lscan[idx] = carry + v - c;
      carry += __shfl(v, 63, 64);
    }
  }
  __syncthreads();
  for (int b = t; b < ncb; b += 256)
    gbase[b] = (cnt[b] > 0) ? atomicAdd(&scount[b], cnt[b]) : 0;
  __syncthreads();
  for (int b = t; b < ncb; b += 256) cnt[b] = 0;
  __syncthreads();
  for (int i = t; i < ne; i += 256) {
    int d = dst[e0 + i], s = src[e0 + i];
    int b = d >> 8;
    int r = atomicAdd(&cnt[b], 1);
    image[lscan[b] + r] =
        (uint32_t)s | ((uint32_t)(d & 255) << 16) | ((uint32_t)b << 24);
  }
  __syncthreads();
  for (int j = t; j < ne; j += 256) {
    uint32_t w = image[j];
    int b = w >> 24;
    int pos = gbase[b] + (j - lscan[b]);
    if (pos < CAPC) tmp[(size_t)b * CAPC + pos] = w & 0xFFFFFFu;
  }
}

// ---------------- bucketB body (uses caller LDS) ----------------
__device__ __forceinline__ void bucketB_body(
    int b, char* smem, const uint32_t* __restrict__ tmp,
    const int* __restrict__ scount, int* __restrict__ row_start,
    int* __restrict__ csr_src, int n, int ncb, int e) {
  int* cnt = (int*)smem;                 // 256
  int* cur = cnt + 256;                  // 256
  int* wsum = cur + 256;                 // 4
  int* s_base = wsum + 4;                // 1
  uint32_t* image = (uint32_t*)(smem + 2080);  // BIMG
  const int t = threadIdx.x, lane = t & 63, wid = t >> 6;

  if (t < 64) {
    int part = 0;
    for (int idx = lane; idx < b; idx += 64) part += scount[idx];
#pragma unroll
    for (int off = 32; off; off >>= 1) part += __shfl_xor(part, off, 64);
    if (lane == 0) *s_base = part;
  }
  cnt[t] = 0;
  __syncthreads();
  const int total = min(scount[b], CAPC);
  const int base = *s_base;
  const uint32_t* strm = tmp + (size_t)b * CAPC;

  for (int i = t; i < total; i += 256) atomicAdd(&cnt[(strm[i] >> 16) & 255], 1);
  __syncthreads();
  int c = cnt[t], v = c;
#pragma unroll
  for (int off = 1; off < 64; off <<= 1) {
    int u = __shfl_up(v, off, 64);
    if (lane >= off) v += u;
  }
  if (lane == 63) wsum[wid] = v;
  __syncthreads();
  if (t == 0) {
    int acc = 0;
#pragma unroll
    for (int w = 0; w < 4; w++) { int x = wsum[w]; wsum[w] = acc; acc += x; }
  }
  __syncthreads();
  int ex = wsum[wid] + v - c;
  cur[t] = ex;
  int d = b * CBG + t;
  if (d < n) row_start[d] = base + ex;
  if (b == 0 && t == 0) row_start[n] = e;
  __syncthreads();
  for (int i = t; i < total; i += 256) {
    uint32_t w = strm[i];
    int dl = (w >> 16) & 255;
    int pos = atomicAdd(&cur[dl], 1);
    if (pos < BIMG) image[pos] = w & 0xFFFFu;
    else csr_src[base + pos] = (int)(w & 0xFFFFu);
  }
  __syncthreads();
  const int lim = total < BIMG ? total : BIMG;
  for (int j = t; j < lim; j += 256) csr_src[base + j] = (int)image[j];
}

// ---------------- MFMA GEMM body (uses caller LDS) ----------------
template <int MODE>
__device__ __forceinline__ void mfmm_body(
    int bid, char* smem,
    const uint32_t* __restrict__ Xp, const short* __restrict__ Whi,
    const short* __restrict__ Wlo, const float* __restrict__ bias,
    uint32_t* __restrict__ Hp, uint32_t* __restrict__ zp,
    float2* __restrict__ el2, float2* __restrict__ er2,
    const float* __restrict__ al, const float* __restrict__ ar, int n,
    const float* __restrict__ emb, const int* __restrict__ ids,
    const float* __restrict__ feat) {
  short* Ahi = (short*)smem;
  short* Alo = Ahi + 64 * 136;
  const int t = threadIdx.x;
  const int nb = bid * 64;

  for (int idx = t; idx < 64 * 32; idx += 256) {
    int nl = idx >> 5, k4 = (idx & 31) << 2;
    int node = nb + nl;
    uint32_t h01 = 0, h23 = 0, l01 = 0, l23 = 0;
    if (node < n) {
      if (MODE == 1) {
        uint4 w = *(const uint4*)&Xp[(size_t)node * 128 + k4];
        h01 = (w.x >> 16) | (w.y & 0xffff0000u);
        l01 = (w.x & 0xffffu) | (w.y << 16);
        h23 = (w.z >> 16) | (w.w & 0xffff0000u);
        l23 = (w.z & 0xffffu) | (w.w << 16);
      } else {
        float4 v;
        if (k4 < 64) v = *(const float4*)&emb[(size_t)ids[node] * 64 + k4];
        else         v = *(const float4*)&feat[(size_t)node * 64 + (k4 - 64)];
        uint32_t a0 = bf16_rne(v.x), a1 = bf16_rne(v.y);
        uint32_t a2 = bf16_rne(v.z), a3 = bf16_rne(v.w);
        h01 = a0 | (a1 << 16);
        h23 = a2 | (a3 << 16);
        l01 = bf16_rne(v.x - __uint_as_float(a0 << 16)) |
              (bf16_rne(v.y - __uint_as_float(a1 << 16)) << 16);
        l23 = bf16_rne(v.z - __uint_as_float(a2 << 16)) |
              (bf16_rne(v.w - __uint_as_float(a3 << 16)) << 16);
      }
    }
    *(uint2*)&Ahi[nl * 136 + k4] = make_uint2(h01, h23);
    *(uint2*)&Alo[nl * 136 + k4] = make_uint2(l01, l23);
  }
  __syncthreads();

  const int lane = t & 63, wv = t >> 6;
  const int r16 = lane & 15, g = lane >> 4;
  const int arow = (wv * 16 + r16) * 136;

  f32x4 acc[8];
#pragma unroll
  for (int c = 0; c < 8; c++) acc[c] = (f32x4){0.f, 0.f, 0.f, 0.f};

#pragma unroll
  for (int q = 0; q < 4; q++) {
    int ka = q * 32 + g * 8;
    short8v ahi = *(const short8v*)&Ahi[arow + ka];
    short8v alo = *(const short8v*)&Alo[arow + ka];
#pragma unroll
    for (int c = 0; c < 8; c++) {
      short8v bhi = *(const short8v*)&Whi[(((q * 8 + c) * 64) + lane) * 8];
      short8v blo = *(const short8v*)&Wlo[(((q * 8 + c) * 64) + lane) * 8];
      acc[c] = __builtin_amdgcn_mfma_f32_16x16x32_bf16(ahi, bhi, acc[c], 0, 0, 0);
      acc[c] = __builtin_amdgcn_mfma_f32_16x16x32_bf16(ahi, blo, acc[c], 0, 0, 0);
      acc[c] = __builtin_amdgcn_mfma_f32_16x16x32_bf16(alo, bhi, acc[c], 0, 0, 0);
    }
  }

  const int node_base = nb + wv * 16;
  if (MODE == 0) {
#pragma unroll
    for (int c = 0; c < 8; c++) {
      int col = c * 16 + r16;
      float bv = bias[col];
#pragma unroll
      for (int r = 0; r < 4; r++) {
        int node = node_base + g * 4 + r;
        if (node < n) {
          float v = fmaxf(acc[c][r] + bv, 0.f);
          Hp[(size_t)node * 128 + col] = pack_hilo(v);
        }
      }
    }
  } else {
    float p0l[4] = {0, 0, 0, 0}, p1l[4] = {0, 0, 0, 0};
    float p0r[4] = {0, 0, 0, 0}, p1r[4] = {0, 0, 0, 0};
#pragma unroll
    for (int c = 0; c < 8; c++) {
      int col = c * 16 + r16;
      float av = al[col], rv = ar[col];
#pragma unroll
      for (int r = 0; r < 4; r++) {
        if (c < 4) { p0l[r] = fmaf(acc[c][r], av, p0l[r]); p0r[r] = fmaf(acc[c][r], rv, p0r[r]); }
        else       { p1l[r] = fmaf(acc[c][r], av, p1l[r]); p1r[r] = fmaf(acc[c][r], rv, p1r[r]); }
      }
    }
#pragma unroll
    for (int c = 0; c < 8; c++) {
#pragma unroll
      for (int r = 0; r < 4; r++) {
        float other = __shfl_xor(acc[c][r], 1, 64);
        int node = node_base + g * 4 + r;
        if (!(lane & 1) && node < n) {
          uint32_t w = bf16_rne(acc[c][r]) | (bf16_rne(other) << 16);
          zp[(size_t)node * 64 + c * 8 + (r16 >> 1)] = w;
        }
      }
    }
#pragma unroll
    for (int off = 1; off < 16; off <<= 1) {
#pragma unroll
      for (int r = 0; r < 4; r++) {
        p0l[r] += __shfl_xor(p0l[r], off, 64);
        p1l[r] += __shfl_xor(p1l[r], off, 64);
        p0r[r] += __shfl_xor(p0r[r], off, 64);
        p1r[r] += __shfl_xor(p1r[r], off, 64);
      }
    }
    if (r16 == 0) {
#pragma unroll
      for (int r = 0; r < 4; r++) {
        int node = node_base + g * 4 + r;
        if (node < n) {
          el2[node] = make_float2(p0l[r], p1l[r]);
          er2[node] = make_float2(p0r[r], p1r[r]);
        }
      }
    }
  }
}

// ---------------- fused: bucketB (blocks [0,ncbB)) + dense GEMM ------------
__global__ __launch_bounds__(256) void mfmm0_bktB_kernel(
    const uint32_t* __restrict__ tmp, const int* __restrict__ scount,
    int* __restrict__ row_start, int* __restrict__ csr_src, int ncbB,
    const short* __restrict__ Whi, const short* __restrict__ Wlo,
    const float* __restrict__ bias, uint32_t* __restrict__ Hp, int n, int ncb,
    int e, const float* __restrict__ emb, const int* __restrict__ ids,
    const float* __restrict__ feat) {
  __shared__ __align__(16) char smem[43040];
  if ((int)blockIdx.x < ncbB) {
    bucketB_body(blockIdx.x, smem, tmp, scount, row_start, csr_src, n, ncb, e);
  } else {
    mfmm_body<0>(blockIdx.x - ncbB, smem, nullptr, Whi, Wlo, bias, Hp,
                 nullptr, nullptr, nullptr, nullptr, nullptr, n, emb, ids, feat);
  }
}

__global__ __launch_bounds__(256) void mfmm1_kernel(
    const uint32_t* __restrict__ Xp, const short* __restrict__ Whi,
    const short* __restrict__ Wlo, uint32_t* __restrict__ zp,
    float2* __restrict__ el2, float2* __restrict__ er2,
    const float* __restrict__ al, const float* __restrict__ ar, int n) {
  __shared__ __align__(16) char smem[64 * 136 * 2 * 2];
  mfmm_body<1>(blockIdx.x, smem, Xp, Whi, Wlo, nullptr, nullptr, zp, el2, er2,
               al, ar, n, nullptr, nullptr, nullptr);
}

// ---------------- fallback path (n >= 65536) ----------------
__global__ void hist_kernel(const int* __restrict__ dst, int* __restrict__ cnt, int e) {
  for (int i = blockIdx.x * blockDim.x + threadIdx.x; i < e; i += gridDim.x * blockDim.x)
    atomicAdd(&cnt[dst[i]], 1);
}
__global__ void scatter_kernel(const int* __restrict__ src, const int* __restrict__ dst,
                               const int* __restrict__ row_start, int* __restrict__ cursor,
                               int* __restrict__ csr_src, int e) {
  for (int i = blockIdx.x * blockDim.x + threadIdx.x; i < e; i += gridDim.x * blockDim.x) {
    int d = dst[i];
    int pos = atomicAdd(&cursor[d], 1);
    csr_src[row_start[d] + pos] = src[i];
  }
}
__global__ __launch_bounds__(1024) void scan1_kernel(const int* __restrict__ cnt,
                                                     int* __restrict__ row_start,
                                                     int* __restrict__ bsum, int n) {
  __shared__ int wsum[16];
  const int t = threadIdx.x, lane = t & 63, wid = t >> 6;
  int i = blockIdx.x * 1024 + t;
  int c = (i < n) ? cnt[i] : 0;
  int v = c;
#pragma unroll
  for (int off = 1; off < 64; off <<= 1) {
    int u = __shfl_up(v, off, 64);
    if (lane >= off) v += u;
  }
  if (lane == 63) wsum[wid] = v;
  __syncthreads();
  if (t == 0) {
    int acc = 0;
#pragma unroll
    for (int w = 0; w < 16; w++) { int x = wsum[w]; wsum[w] = acc; acc += x; }
    bsum[blockIdx.x] = acc;
  }
  __syncthreads();
  if (i < n) row_start[i] = wsum[wid] + v - c;
}
__global__ __launch_bounds__(64) void scan2_kernel(int* __restrict__ bsum, int nb) {
  const int lane = threadIdx.x;
  int carry = 0;
  for (int base = 0; base < nb; base += 64) {
    int idx = base + lane;
    int c = (idx < nb) ? bsum[idx] : 0;
    int v = c;
#pragma unroll
    for (int off = 1; off < 64; off <<= 1) {
      int u = __shfl_up(v, off, 64);
      if (lane >= off) v += u;
    }
    if (idx < nb) bsum[idx] = carry + v - c;
    carry += __shfl(v, 63, 64);
  }
}
__global__ void scan3_kernel(int* __restrict__ row_start, const int* __restrict__ bsum,
                             int n, int e) {
  int i = blockIdx.x * blockDim.x + threadIdx.x;
  if (i < n) row_start[i] += bsum[i >> 10];
  if (i == 0) row_start[n] = e;
}

// ---------------- GAT aggregation (wave per dst node) -- r6 structure ------
#define CAP 256
__global__ __launch_bounds__(256) void agg12_kernel(
    const uint32_t* __restrict__ zp, const float2* __restrict__ el2,
    const float2* __restrict__ er2, const int* __restrict__ row_start,
    const int* __restrict__ csr_src, const float* __restrict__ bias,
    uint32_t* __restrict__ Hp,
    const float* __restrict__ ow, const float* __restrict__ oal,
    const float* __restrict__ oar, float* __restrict__ z3,
    float* __restrict__ el3, float* __restrict__ er3, int n, int fuse_out) {
  __shared__ float2 ec[4][CAP];
  __shared__ int sc[4][CAP];
  const int w = threadIdx.x >> 6, lane = threadIdx.x & 63;
  const int node = blockIdx.x * 4 + w;
  const bool valid = node < n;
  int rs = 0, deg = 0;
  float er0 = 0.f, er1 = 0.f;
  if (valid) {
    rs = row_start[node];
    deg = row_start[node + 1] - rs;
    float2 e2 = er2[node];
    er0 = e2.x; er1 = e2.y;
  }
  const int cdeg = deg < CAP ? deg : CAP;

  float sp0 = 0.f, sp1 = 0.f;
  for (int i = lane; i < deg; i += 64) {
    int s = csr_src[rs + i];
    float2 l = el2[s];
    float x0 = __expf(lrelu(l.x + er0));
    float x1 = __expf(lrelu(l.y + er1));
    if (i < CAP) { sc[w][i] = s; ec[w][i] = make_float2(x0, x1); }
    sp0 += x0; sp1 += x1;
  }
#pragma unroll
  for (int off = 32; off; off >>= 1) {
    sp0 += __shfl_xor(sp0, off, 64);
    sp1 += __shfl_xor(sp1, off, 64);
  }
  __syncthreads();

  float ae = 0.f, ao = 0.f;
  int i = 0;
  for (; i + 8 <= cdeg; i += 8) {
    uint32_t zw[8];
    float xh[8];
#pragma unroll
    for (int u = 0; u < 8; u++) {
      int s = sc[w][i + u];
      float2 ex = ec[w][i + u];
      xh[u] = (lane < 32) ? ex.x : ex.y;
      zw[u] = zp[(size_t)s * 64 + lane];
    }
#pragma unroll
    for (int u = 0; u < 8; u++) {
      ae = fmaf(xh[u], __uint_as_float(zw[u] << 16), ae);
      ao = fmaf(xh[u], __uint_as_float(zw[u] & 0xffff0000u), ao);
    }
  }
  for (; i < cdeg; i++) {
    int s = sc[w][i];
    float2 ex = ec[w][i];
    float x = (lane < 32) ? ex.x : ex.y;
    uint32_t zw = zp[(size_t)s * 64 + lane];
    ae = fmaf(x, __uint_as_float(zw << 16), ae);
    ao = fmaf(x, __uint_as_float(zw & 0xffff0000u), ao);
  }
  for (; i < deg; i++) {
    int s = csr_src[rs + i];
    float2 l = el2[s];
    float x0 = __expf(lrelu(l.x + er0));
    float x1 = __expf(lrelu(l.y + er1));
    float x = (lane < 32) ? x0 : x1;
    uint32_t zw = zp[(size_t)s * 64 + lane];
    ae = fmaf(x, __uint_as_float(zw << 16), ae);
    ao = fmaf(x, __uint_as_float(zw & 0xffff0000u), ao);
  }

  if (valid) {
    float sp = (lane < 32) ? sp0 : sp1;
    float2 b2 = reinterpret_cast<const float2*>(bias)[lane];
    float oe, oo;
    if (deg == 0) { oe = b2.x; oo = b2.y; }
    else { oe = ae / sp + b2.x; oo = ao / sp + b2.y; }
    oe = fmaxf(oe, 0.f);
    oo = fmaxf(oo, 0.f);
    if (!fuse_out) {
      *(uint2*)&Hp[(size_t)node * 128 + 2 * lane] =
          make_uint2(pack_hilo(oe), pack_hilo(oo));
    } else {
      float2 w2 = reinterpret_cast<const float2*>(ow)[lane];
      float d = oe * w2.x + oo * w2.y;
#pragma unroll
      for (int off = 32; off; off >>= 1) d += __shfl_xor(d, off, 64);
      if (lane == 0) {
        z3[node] = d;
        el3[node] = d * oal[0];
        er3[node] = d * oar[0];
      }
    }
  }
}

// ---------------- output GAT layer: 32-lane group per node -----------------
__global__ __launch_bounds__(256) void agg3_kernel(
    const float* __restrict__ z3, const float* __restrict__ el3,
    const float* __restrict__ er3, const int* __restrict__ row_start,
    const int* __restrict__ csr_src, const float* __restrict__ b,
    float* __restrict__ out, int n) {
  int node = blockIdx.x * 8 + (threadIdx.x >> 5);
  int l32 = threadIdx.x & 31;
  if (node >= n) return;
  int rs = row_start[node];
  int deg = row_start[node + 1] - rs;
  float er = er3[node];
  float sp = 0.f, ap = 0.f;
  for (int i = l32; i < deg; i += 32) {
    int s = csr_src[rs + i];
    float ex = __expf(lrelu(el3[s] + er));
    sp += ex;
    ap = fmaf(ex, z3[s], ap);
  }
#pragma unroll
  for (int off = 16; off; off >>= 1) {
    sp += __shfl_xor(sp, off, 64);
    ap += __shfl_xor(ap, off, 64);
  }
  if (l32 == 0) out[node] = (deg == 0) ? b[0] : (ap / sp + b[0]);
}

// ---------------------------------------------------------------------------
extern "C" void kernel_launch(void* const* d_in, const int* in_sizes, int n_in,
                              void* d_out, int out_size, void* d_ws, size_t ws_size,
                              hipStream_t stream) {
  const float* feat     = (const float*)d_in[0];
  const int*   node_ids = (const int*)d_in[1];
  const int*   src      = (const int*)d_in[2];
  const int*   dst      = (const int*)d_in[3];
  const float* emb      = (const float*)d_in[4];
  const float* dense_w  = (const float*)d_in[5];
  const float* dense_b  = (const float*)d_in[6];
  const float* g1_w     = (const float*)d_in[7];
  const float* g1_al    = (const float*)d_in[8];
  const float* g1_ar    = (const float*)d_in[9];
  const float* g1_b     = (const float*)d_in[10];
  const float* g2_w     = (const float*)d_in[11];
  const float* g2_al    = (const float*)d_in[12];
  const float* g2_ar    = (const float*)d_in[13];
  const float* g2_b     = (const float*)d_in[14];
  const float* out_w    = (const float*)d_in[15];
  const float* out_al   = (const float*)d_in[16];
  const float* out_ar   = (const float*)d_in[17];
  const float* out_b    = (const float*)d_in[18];
  const int n = in_sizes[0] / 64;   // 50000
  const int e = in_sizes[2];        // 1600000

  const int ncb = (n + CBG - 1) / CBG;

  char* ws = (char*)d_ws;
  size_t off = 0;
  auto alloc = [&](size_t bytes) -> void* {
    void* p = ws + off;
    off += (bytes + 255) & ~(size_t)255;
    return p;
  };
  uint32_t* Hp       = (uint32_t*)alloc((size_t)n * 128 * 4);
  size_t zp_bytes    = (size_t)n * 64 * 4;
  size_t tmp_bytes   = (size_t)ncb * CAPC * 4;
  uint32_t* zp       = (uint32_t*)alloc(zp_bytes > tmp_bytes ? zp_bytes : tmp_bytes);
  uint32_t* tmp      = zp;
  float2*   el2      = (float2*)alloc((size_t)n * 8);
  float2*   er2      = (float2*)alloc((size_t)n * 8);
  float*    z3       = (float*)alloc((size_t)n * 4);
  float*    el3      = (float*)alloc((size_t)n * 4);
  float*    er3      = (float*)alloc((size_t)n * 4);
  int*      scount   = (int*)alloc((size_t)ncb * 4);
  int*      row_start= (int*)alloc((size_t)(n + 1) * 4);
  int*      csr_src  = (int*)alloc((size_t)e * 4);
  short*    Wd_hi    = (short*)alloc(2048 * 8 * 2);
  short*    Wd_lo    = (short*)alloc(2048 * 8 * 2);
  short*    W1_hi    = (short*)alloc(2048 * 8 * 2);
  short*    W1_lo    = (short*)alloc(2048 * 8 * 2);
  short*    W2_hi    = (short*)alloc(2048 * 8 * 2);
  short*    W2_lo    = (short*)alloc(2048 * 8 * 2);
  // fallback-only buffers
  int*      cnt      = (int*)alloc((size_t)n * 4);
  int*      cursor   = (int*)alloc((size_t)n * 4);
  const int nblk     = (n + 1023) / 1024;
  int*      bsum     = (int*)alloc((size_t)nblk * 4);

  const int mmgrid = (n + 63) / 64;
  const int ngrid4 = (n + 3) / 4;
  const int ngrid8 = (n + 7) / 8;

  // prep: W split+swizzle + scount zero (one launch)
  prep_kernel<<<25, 256, 0, stream>>>(dense_w, g1_w, g2_w,
                                      Wd_hi, Wd_lo, W1_hi, W1_lo, W2_hi, W2_lo,
                                      scount, ncb);

  if (n < 65536) {
    const int natile = (e + TILE - 1) / TILE;
    bucketA_kernel<<<natile, 256, 0, stream>>>(src, dst, scount, tmp, e, ncb);
    // fused: bucketB (first ncb blocks) + dense GEMM (remaining mmgrid blocks)
    mfmm0_bktB_kernel<<<ncb + mmgrid, 256, 0, stream>>>(
        tmp, scount, row_start, csr_src, ncb,
        Wd_hi, Wd_lo, dense_b, Hp, n, ncb, e, emb, node_ids, feat);
  } else {
    hipMemsetAsync(cnt, 0, (size_t)n * 4, stream);
    hipMemsetAsync(cursor, 0, (size_t)n * 4, stream);
    hist_kernel<<<2048, 256, 0, stream>>>(dst, cnt, e);
    scan1_kernel<<<nblk, 1024, 0, stream>>>(cnt, row_start, bsum, n);
    scan2_kernel<<<1, 64, 0, stream>>>(bsum, nblk);
    scan3_kernel<<<(n + 255) / 256, 256, 0, stream>>>(row_start, bsum, n, e);
    scatter_kernel<<<2048, 256, 0, stream>>>(src, dst, row_start, cursor, csr_src, e);
    // dense GEMM alone (ncbB = 0)
    mfmm0_bktB_kernel<<<mmgrid, 256, 0, stream>>>(
        tmp, scount, row_start, csr_src, 0,
        Wd_hi, Wd_lo, dense_b, Hp, n, ncb, e, emb, node_ids, feat);
  }

  // GAT layer 1
  mfmm1_kernel<<<mmgrid, 256, 0, stream>>>(Hp, W1_hi, W1_lo, zp, el2, er2,
                                           g1_al, g1_ar, n);
  agg12_kernel<<<ngrid4, 256, 0, stream>>>(zp, el2, er2, row_start, csr_src, g1_b, Hp,
                                           nullptr, nullptr, nullptr, nullptr, nullptr,
                                           nullptr, n, 0);
  // GAT layer 2 (+ fused output-layer z3/el3/er3)
  mfmm1_kernel<<<mmgrid, 256, 0, stream>>>(Hp, W2_hi, W2_lo, zp, el2, er2,
                                           g2_al, g2_ar, n);
  agg12_kernel<<<ngrid4, 256, 0, stream>>>(zp, el2, er2, row_start, csr_src, g2_b, nullptr,
                                           out_w, out_al, out_ar, z3, el3, er3, n, 1);
  // output GAT layer aggregation
  agg3_kernel<<<ngrid8, 256, 0, stream>>>(z3, el3, er3, row_start, csr_src, out_b,
                                          (float*)d_out, n);
}

// Round 10
// 232.864 us; speedup vs baseline: 1.1418x; 1.0210x over previous
//
#include <hip/hip_runtime.h>
#include <cfloat>
#include <cmath>

// ---------------------------------------------------------------------------
// UncertaintyGAT. Round-10: src-block-sorted adjacency.
//  bucketB counting-sort key extended to (dst_local*8 + src_block): each dst's
//  neighbor list comes out ordered by src block (~1.6MB bands of zp). All
//  concurrent agg12 waves walk blocks 0..7 in lockstep-ish order -> the
//  instantaneous gather working set fits an XCD's 4MB L2 (was: random over
//  12.8MB, 62% hit, 155MB fetch). agg12 itself unchanged (r6/r8 operating
//  point: 8-unroll, 32 VGPR). bucketA TILE back to 4096 (r9's 2048 made
//  copy-out runs sub-line). Everything else as r9.
// ---------------------------------------------------------------------------

#define CBG 256
#define CAPC 12288
#define TILE 4096
#define BIMG 10240

typedef __attribute__((ext_vector_type(8))) short short8v;
typedef __attribute__((ext_vector_type(4))) float f32x4;

__device__ __forceinline__ float lrelu(float x) { return x > 0.f ? x : 0.2f * x; }

__device__ __forceinline__ uint32_t bf16_rne(float f) {
  uint32_t u = __float_as_uint(f);
  return (u + 0x7fffu + ((u >> 16) & 1u)) >> 16;
}
__device__ __forceinline__ uint32_t pack_hilo(float v) {
  uint32_t h = bf16_rne(v);
  float r = v - __uint_as_float(h << 16);
  return (h << 16) | bf16_rne(r);
}

// ---------------- prep: W split+swizzle (blocks 0..23) + scount zero -------
__global__ __launch_bounds__(256) void prep_kernel(
    const float* __restrict__ W0, const float* __restrict__ W1,
    const float* __restrict__ W2, short* __restrict__ Whi0,
    short* __restrict__ Wlo0, short* __restrict__ Whi1, short* __restrict__ Wlo1,
    short* __restrict__ Whi2, short* __restrict__ Wlo2,
    int* __restrict__ scount, int ncb) {
  if (blockIdx.x >= 24) {
    for (int i = threadIdx.x; i < ncb; i += 256) scount[i] = 0;
    return;
  }
  int which = blockIdx.x >> 3;
  const float* W = which == 0 ? W0 : (which == 1 ? W1 : W2);
  short* Whi = which == 0 ? Whi0 : (which == 1 ? Whi1 : Whi2);
  short* Wlo = which == 0 ? Wlo0 : (which == 1 ? Wlo1 : Wlo2);
  int fid = (blockIdx.x & 7) * 256 + threadIdx.x;  // 0..2047
  int lane = fid & 63;
  int cq = fid >> 6;
  int q = cq >> 3, c = cq & 7;
  int col = c * 16 + (lane & 15);
  int k0 = q * 32 + (lane >> 4) * 8;
#pragma unroll
  for (int j = 0; j < 8; j++) {
    float v = W[(k0 + j) * 128 + col];
    uint32_t h = bf16_rne(v);
    float r = v - __uint_as_float(h << 16);
    Whi[fid * 8 + j] = (short)h;
    Wlo[fid * 8 + j] = (short)bf16_rne(r);
  }
}

// ---------------- CSR build (n < 65536 path) ----------------
__global__ __launch_bounds__(256) void bucketA_kernel(
    const int* __restrict__ src, const int* __restrict__ dst,
    int* __restrict__ scount, uint32_t* __restrict__ tmp, int e, int ncb) {
  __shared__ int cnt[256];
  __shared__ int lscan[256];
  __shared__ int gbase[256];
  __shared__ uint32_t image[TILE];
  const int t = threadIdx.x;
  const int e0 = blockIdx.x * TILE;
  const int ne = min(TILE, e - e0);

  for (int i = t; i < 256; i += 256) cnt[i] = 0;
  __syncthreads();
  for (int i = t; i < ne; i += 256) atomicAdd(&cnt[dst[e0 + i] >> 8], 1);
  __syncthreads();
  if (t < 64) {
    int carry = 0;
    for (int base = 0; base < ncb; base += 64) {
      int idx = base + t;
      int c = (idx < ncb) ? cnt[idx] : 0;
      int v = c;
#pragma unroll
      for (int off = 1; off < 64; off <<= 1) {
        int u = __shfl_up(v, off, 64);
        if (t >= off) v += u;
      }
      if (idx < ncb) lscan[idx] = carry + v - c;
      carry += __shfl(v, 63, 64);
    }
  }
  __syncthreads();
  for (int b = t; b < ncb; b += 256)
    gbase[b] = (cnt[b] > 0) ? atomicAdd(&scount[b], cnt[b]) : 0;
  __syncthreads();
  for (int b = t; b < ncb; b += 256) cnt[b] = 0;
  __syncthreads();
  for (int i = t; i < ne; i += 256) {
    int d = dst[e0 + i], s = src[e0 + i];
    int b = d >> 8;
    int r = atomicAdd(&cnt[b], 1);
    image[lscan[b] + r] =
        (uint32_t)s | ((uint32_t)(d & 255) << 16) | ((uint32_t)b << 24);
  }
  __syncthreads();
  for (int j = t; j < ne; j += 256) {
    uint32_t w = image[j];
    int b = w >> 24;
    int pos = gbase[b] + (j - lscan[b]);
    if (pos < CAPC) tmp[(size_t)b * CAPC + pos] = w & 0xFFFFFFu;
  }
}

// ---------------- bucketB body: key = dst_local*8 + src_block --------------
__device__ __forceinline__ void bucketB_body(
    int b, char* smem, const uint32_t* __restrict__ tmp,
    const int* __restrict__ scount, int* __restrict__ row_start,
    int* __restrict__ csr_src, int n, int ncb, int e, int sshift) {
  int* cnt2 = (int*)smem;                      // 2048 (hist -> cursor)
  int* wsum = cnt2 + 2048;                     // 4
  int* s_base = wsum + 4;                      // 1
  uint32_t* image = (uint32_t*)(smem + 8224);  // BIMG
  const int t = threadIdx.x, lane = t & 63, wid = t >> 6;

  if (t < 64) {
    int part = 0;
    for (int idx = lane; idx < b; idx += 64) part += scount[idx];
#pragma unroll
    for (int off = 32; off; off >>= 1) part += __shfl_xor(part, off, 64);
    if (lane == 0) *s_base = part;
  }
#pragma unroll
  for (int j = 0; j < 8; j++) cnt2[t * 8 + j] = 0;
  __syncthreads();
  const int total = min(scount[b], CAPC);
  const int base = *s_base;
  const uint32_t* strm = tmp + (size_t)b * CAPC;

  // histogram over (dst_local, src_block)
  for (int i = t; i < total; i += 256) {
    uint32_t w = strm[i];
    int key = (((w >> 16) & 255) << 3) + ((w & 0xFFFFu) >> sshift);
    atomicAdd(&cnt2[key], 1);
  }
  __syncthreads();
  // thread t owns dst t: local scan of its 8 sub-counters, then 256-scan
  int c8[8];
  int run = 0;
#pragma unroll
  for (int j = 0; j < 8; j++) { int x = cnt2[t * 8 + j]; c8[j] = run; run += x; }
  int c = run, v = c;
#pragma unroll
  for (int off = 1; off < 64; off <<= 1) {
    int u = __shfl_up(v, off, 64);
    if (lane >= off) v += u;
  }
  if (lane == 63) wsum[wid] = v;
  __syncthreads();
  if (t == 0) {
    int acc = 0;
#pragma unroll
    for (int w = 0; w < 4; w++) { int x = wsum[w]; wsum[w] = acc; acc += x; }
  }
  __syncthreads();
  int ex = wsum[wid] + v - c;
#pragma unroll
  for (int j = 0; j < 8; j++) cnt2[t * 8 + j] = ex + c8[j];
  int d = b * CBG + t;
  if (d < n) row_start[d] = base + ex;
  if (b == 0 && t == 0) row_start[n] = e;
  __syncthreads();
  // scatter src16 into src-block-sorted position
  for (int i = t; i < total; i += 256) {
    uint32_t w = strm[i];
    uint32_t s = w & 0xFFFFu;
    int key = (((w >> 16) & 255) << 3) + (s >> sshift);
    int pos = atomicAdd(&cnt2[key], 1);
    if (pos < BIMG) image[pos] = s;
    else csr_src[base + pos] = (int)s;
  }
  __syncthreads();
  const int lim = total < BIMG ? total : BIMG;
  for (int j = t; j < lim; j += 256) csr_src[base + j] = (int)image[j];
}

// ---------------- MFMA GEMM body (uses caller LDS) ----------------
template <int MODE>
__device__ __forceinline__ void mfmm_body(
    int bid, char* smem,
    const uint32_t* __restrict__ Xp, const short* __restrict__ Whi,
    const short* __restrict__ Wlo, const float* __restrict__ bias,
    uint32_t* __restrict__ Hp, uint32_t* __restrict__ zp,
    float2* __restrict__ el2, float2* __restrict__ er2,
    const float* __restrict__ al, const float* __restrict__ ar, int n,
    const float* __restrict__ emb, const int* __restrict__ ids,
    const float* __restrict__ feat) {
  short* Ahi = (short*)smem;
  short* Alo = Ahi + 64 * 136;
  const int t = threadIdx.x;
  const int nb = bid * 64;

  for (int idx = t; idx < 64 * 32; idx += 256) {
    int nl = idx >> 5, k4 = (idx & 31) << 2;
    int node = nb + nl;
    uint32_t h01 = 0, h23 = 0, l01 = 0, l23 = 0;
    if (node < n) {
      if (MODE == 1) {
        uint4 w = *(const uint4*)&Xp[(size_t)node * 128 + k4];
        h01 = (w.x >> 16) | (w.y & 0xffff0000u);
        l01 = (w.x & 0xffffu) | (w.y << 16);
        h23 = (w.z >> 16) | (w.w & 0xffff0000u);
        l23 = (w.z & 0xffffu) | (w.w << 16);
      } else {
        float4 v;
        if (k4 < 64) v = *(const float4*)&emb[(size_t)ids[node] * 64 + k4];
        else         v = *(const float4*)&feat[(size_t)node * 64 + (k4 - 64)];
        uint32_t a0 = bf16_rne(v.x), a1 = bf16_rne(v.y);
        uint32_t a2 = bf16_rne(v.z), a3 = bf16_rne(v.w);
        h01 = a0 | (a1 << 16);
        h23 = a2 | (a3 << 16);
        l01 = bf16_rne(v.x - __uint_as_float(a0 << 16)) |
              (bf16_rne(v.y - __uint_as_float(a1 << 16)) << 16);
        l23 = bf16_rne(v.z - __uint_as_float(a2 << 16)) |
              (bf16_rne(v.w - __uint_as_float(a3 << 16)) << 16);
      }
    }
    *(uint2*)&Ahi[nl * 136 + k4] = make_uint2(h01, h23);
    *(uint2*)&Alo[nl * 136 + k4] = make_uint2(l01, l23);
  }
  __syncthreads();

  const int lane = t & 63, wv = t >> 6;
  const int r16 = lane & 15, g = lane >> 4;
  const int arow = (wv * 16 + r16) * 136;

  f32x4 acc[8];
#pragma unroll
  for (int c = 0; c < 8; c++) acc[c] = (f32x4){0.f, 0.f, 0.f, 0.f};

#pragma unroll
  for (int q = 0; q < 4; q++) {
    int ka = q * 32 + g * 8;
    short8v ahi = *(const short8v*)&Ahi[arow + ka];
    short8v alo = *(const short8v*)&Alo[arow + ka];
#pragma unroll
    for (int c = 0; c < 8; c++) {
      short8v bhi = *(const short8v*)&Whi[(((q * 8 + c) * 64) + lane) * 8];
      short8v blo = *(const short8v*)&Wlo[(((q * 8 + c) * 64) + lane) * 8];
      acc[c] = __builtin_amdgcn_mfma_f32_16x16x32_bf16(ahi, bhi, acc[c], 0, 0, 0);
      acc[c] = __builtin_amdgcn_mfma_f32_16x16x32_bf16(ahi, blo, acc[c], 0, 0, 0);
      acc[c] = __builtin_amdgcn_mfma_f32_16x16x32_bf16(alo, bhi, acc[c], 0, 0, 0);
    }
  }

  const int node_base = nb + wv * 16;
  if (MODE == 0) {
#pragma unroll
    for (int c = 0; c < 8; c++) {
      int col = c * 16 + r16;
      float bv = bias[col];
#pragma unroll
      for (int r = 0; r < 4; r++) {
        int node = node_base + g * 4 + r;
        if (node < n) {
          float v = fmaxf(acc[c][r] + bv, 0.f);
          Hp[(size_t)node * 128 + col] = pack_hilo(v);
        }
      }
    }
  } else {
    float p0l[4] = {0, 0, 0, 0}, p1l[4] = {0, 0, 0, 0};
    float p0r[4] = {0, 0, 0, 0}, p1r[4] = {0, 0, 0, 0};
#pragma unroll
    for (int c = 0; c < 8; c++) {
      int col = c * 16 + r16;
      float av = al[col], rv = ar[col];
#pragma unroll
      for (int r = 0; r < 4; r++) {
        if (c < 4) { p0l[r] = fmaf(acc[c][r], av, p0l[r]); p0r[r] = fmaf(acc[c][r], rv, p0r[r]); }
        else       { p1l[r] = fmaf(acc[c][r], av, p1l[r]); p1r[r] = fmaf(acc[c][r], rv, p1r[r]); }
      }
    }
#pragma unroll
    for (int c = 0; c < 8; c++) {
#pragma unroll
      for (int r = 0; r < 4; r++) {
        float other = __shfl_xor(acc[c][r], 1, 64);
        int node = node_base + g * 4 + r;
        if (!(lane & 1) && node < n) {
          uint32_t w = bf16_rne(acc[c][r]) | (bf16_rne(other) << 16);
          zp[(size_t)node * 64 + c * 8 + (r16 >> 1)] = w;
        }
      }
    }
#pragma unroll
    for (int off = 1; off < 16; off <<= 1) {
#pragma unroll
      for (int r = 0; r < 4; r++) {
        p0l[r] += __shfl_xor(p0l[r], off, 64);
        p1l[r] += __shfl_xor(p1l[r], off, 64);
        p0r[r] += __shfl_xor(p0r[r], off, 64);
        p1r[r] += __shfl_xor(p1r[r], off, 64);
      }
    }
    if (r16 == 0) {
#pragma unroll
      for (int r = 0; r < 4; r++) {
        int node = node_base + g * 4 + r;
        if (node < n) {
          el2[node] = make_float2(p0l[r], p1l[r]);
          er2[node] = make_float2(p0r[r], p1r[r]);
        }
      }
    }
  }
}

// ---------------- fused: bucketB (blocks [0,ncbB)) + dense GEMM ------------
__global__ __launch_bounds__(256) void mfmm0_bktB_kernel(
    const uint32_t* __restrict__ tmp, const int* __restrict__ scount,
    int* __restrict__ row_start, int* __restrict__ csr_src, int ncbB,
    const short* __restrict__ Whi, const short* __restrict__ Wlo,
    const float* __restrict__ bias, uint32_t* __restrict__ Hp, int n, int ncb,
    int e, int sshift, const float* __restrict__ emb, const int* __restrict__ ids,
    const float* __restrict__ feat) {
  __shared__ __align__(16) char smem[49200];
  if ((int)blockIdx.x < ncbB) {
    bucketB_body(blockIdx.x, smem, tmp, scount, row_start, csr_src, n, ncb, e,
                 sshift);
  } else {
    mfmm_body<0>(blockIdx.x - ncbB, smem, nullptr, Whi, Wlo, bias, Hp,
                 nullptr, nullptr, nullptr, nullptr, nullptr, n, emb, ids, feat);
  }
}

__global__ __launch_bounds__(256) void mfmm1_kernel(
    const uint32_t* __restrict__ Xp, const short* __restrict__ Whi,
    const short* __restrict__ Wlo, uint32_t* __restrict__ zp,
    float2* __restrict__ el2, float2* __restrict__ er2,
    const float* __restrict__ al, const float* __restrict__ ar, int n) {
  __shared__ __align__(16) char smem[64 * 136 * 2 * 2];
  mfmm_body<1>(blockIdx.x, smem, Xp, Whi, Wlo, nullptr, nullptr, zp, el2, er2,
               al, ar, n, nullptr, nullptr, nullptr);
}

// ---------------- fallback path (n >= 65536) ----------------
__global__ void hist_kernel(const int* __restrict__ dst, int* __restrict__ cnt, int e) {
  for (int i = blockIdx.x * blockDim.x + threadIdx.x; i < e; i += gridDim.x * blockDim.x)
    atomicAdd(&cnt[dst[i]], 1);
}
__global__ void scatter_kernel(const int* __restrict__ src, const int* __restrict__ dst,
                               const int* __restrict__ row_start, int* __restrict__ cursor,
                               int* __restrict__ csr_src, int e) {
  for (int i = blockIdx.x * blockDim.x + threadIdx.x; i < e; i += gridDim.x * blockDim.x) {
    int d = dst[i];
    int pos = atomicAdd(&cursor[d], 1);
    csr_src[row_start[d] + pos] = src[i];
  }
}
__global__ __launch_bounds__(1024) void scan1_kernel(const int* __restrict__ cnt,
                                                     int* __restrict__ row_start,
                                                     int* __restrict__ bsum, int n) {
  __shared__ int wsum[16];
  const int t = threadIdx.x, lane = t & 63, wid = t >> 6;
  int i = blockIdx.x * 1024 + t;
  int c = (i < n) ? cnt[i] : 0;
  int v = c;
#pragma unroll
  for (int off = 1; off < 64; off <<= 1) {
    int u = __shfl_up(v, off, 64);
    if (lane >= off) v += u;
  }
  if (lane == 63) wsum[wid] = v;
  __syncthreads();
  if (t == 0) {
    int acc = 0;
#pragma unroll
    for (int w = 0; w < 16; w++) { int x = wsum[w]; wsum[w] = acc; acc += x; }
    bsum[blockIdx.x] = acc;
  }
  __syncthreads();
  if (i < n) row_start[i] = wsum[wid] + v - c;
}
__global__ __launch_bounds__(64) void scan2_kernel(int* __restrict__ bsum, int nb) {
  const int lane = threadIdx.x;
  int carry = 0;
  for (int base = 0; base < nb; base += 64) {
    int idx = base + lane;
    int c = (idx < nb) ? bsum[idx] : 0;
    int v = c;
#pragma unroll
    for (int off = 1; off < 64; off <<= 1) {
      int u = __shfl_up(v, off, 64);
      if (lane >= off) v += u;
    }
    if (idx < nb) bsum[idx] = carry + v - c;
    carry += __shfl(v, 63, 64);
  }
}
__global__ void scan3_kernel(int* __restrict__ row_start, const int* __restrict__ bsum,
                             int n, int e) {
  int i = blockIdx.x * blockDim.x + threadIdx.x;
  if (i < n) row_start[i] += bsum[i >> 10];
  if (i == 0) row_start[n] = e;
}

// ---------------- GAT aggregation (wave per dst node) -- r6 structure ------
#define CAP 256
__global__ __launch_bounds__(256) void agg12_kernel(
    const uint32_t* __restrict__ zp, const float2* __restrict__ el2,
    const float2* __restrict__ er2, const int* __restrict__ row_start,
    const int* __restrict__ csr_src, const float* __restrict__ bias,
    uint32_t* __restrict__ Hp,
    const float* __restrict__ ow, const float* __restrict__ oal,
    const float* __restrict__ oar, float* __restrict__ z3,
    float* __restrict__ el3, float* __restrict__ er3, int n, int fuse_out) {
  __shared__ float2 ec[4][CAP];
  __shared__ int sc[4][CAP];
  const int w = threadIdx.x >> 6, lane = threadIdx.x & 63;
  const int node = blockIdx.x * 4 + w;
  const bool valid = node < n;
  int rs = 0, deg = 0;
  float er0 = 0.f, er1 = 0.f;
  if (valid) {
    rs = row_start[node];
    deg = row_start[node + 1] - rs;
    float2 e2 = er2[node];
    er0 = e2.x; er1 = e2.y;
  }
  const int cdeg = deg < CAP ? deg : CAP;

  float sp0 = 0.f, sp1 = 0.f;
  for (int i = lane; i < deg; i += 64) {
    int s = csr_src[rs + i];
    float2 l = el2[s];
    float x0 = __expf(lrelu(l.x + er0));
    float x1 = __expf(lrelu(l.y + er1));
    if (i < CAP) { sc[w][i] = s; ec[w][i] = make_float2(x0, x1); }
    sp0 += x0; sp1 += x1;
  }
#pragma unroll
  for (int off = 32; off; off >>= 1) {
    sp0 += __shfl_xor(sp0, off, 64);
    sp1 += __shfl_xor(sp1, off, 64);
  }
  __syncthreads();

  float ae = 0.f, ao = 0.f;
  int i = 0;
  for (; i + 8 <= cdeg; i += 8) {
    uint32_t zw[8];
    float xh[8];
#pragma unroll
    for (int u = 0; u < 8; u++) {
      int s = sc[w][i + u];
      float2 ex = ec[w][i + u];
      xh[u] = (lane < 32) ? ex.x : ex.y;
      zw[u] = zp[(size_t)s * 64 + lane];
    }
#pragma unroll
    for (int u = 0; u < 8; u++) {
      ae = fmaf(xh[u], __uint_as_float(zw[u] << 16), ae);
      ao = fmaf(xh[u], __uint_as_float(zw[u] & 0xffff0000u), ao);
    }
  }
  for (; i < cdeg; i++) {
    int s = sc[w][i];
    float2 ex = ec[w][i];
    float x = (lane < 32) ? ex.x : ex.y;
    uint32_t zw = zp[(size_t)s * 64 + lane];
    ae = fmaf(x, __uint_as_float(zw << 16), ae);
    ao = fmaf(x, __uint_as_float(zw & 0xffff0000u), ao);
  }
  for (; i < deg; i++) {
    int s = csr_src[rs + i];
    float2 l = el2[s];
    float x0 = __expf(lrelu(l.x + er0));
    float x1 = __expf(lrelu(l.y + er1));
    float x = (lane < 32) ? x0 : x1;
    uint32_t zw = zp[(size_t)s * 64 + lane];
    ae = fmaf(x, __uint_as_float(zw << 16), ae);
    ao = fmaf(x, __uint_as_float(zw & 0xffff0000u), ao);
  }

  if (valid) {
    float sp = (lane < 32) ? sp0 : sp1;
    float2 b2 = reinterpret_cast<const float2*>(bias)[lane];
    float oe, oo;
    if (deg == 0) { oe = b2.x; oo = b2.y; }
    else { oe = ae / sp + b2.x; oo = ao / sp + b2.y; }
    oe = fmaxf(oe, 0.f);
    oo = fmaxf(oo, 0.f);
    if (!fuse_out) {
      *(uint2*)&Hp[(size_t)node * 128 + 2 * lane] =
          make_uint2(pack_hilo(oe), pack_hilo(oo));
    } else {
      float2 w2 = reinterpret_cast<const float2*>(ow)[lane];
      float d = oe * w2.x + oo * w2.y;
#pragma unroll
      for (int off = 32; off; off >>= 1) d += __shfl_xor(d, off, 64);
      if (lane == 0) {
        z3[node] = d;
        el3[node] = d * oal[0];
        er3[node] = d * oar[0];
      }
    }
  }
}

// ---------------- output GAT layer: 32-lane group per node -----------------
__global__ __launch_bounds__(256) void agg3_kernel(
    const float* __restrict__ z3, const float* __restrict__ el3,
    const float* __restrict__ er3, const int* __restrict__ row_start,
    const int* __restrict__ csr_src, const float* __restrict__ b,
    float* __restrict__ out, int n) {
  int node = blockIdx.x * 8 + (threadIdx.x >> 5);
  int l32 = threadIdx.x & 31;
  if (node >= n) return;
  int rs = row_start[node];
  int deg = row_start[node + 1] - rs;
  float er = er3[node];
  float sp = 0.f, ap = 0.f;
  for (int i = l32; i < deg; i += 32) {
    int s = csr_src[rs + i];
    float ex = __expf(lrelu(el3[s] + er));
    sp += ex;
    ap = fmaf(ex, z3[s], ap);
  }
#pragma unroll
  for (int off = 16; off; off >>= 1) {
    sp += __shfl_xor(sp, off, 64);
    ap += __shfl_xor(ap, off, 64);
  }
  if (l32 == 0) out[node] = (deg == 0) ? b[0] : (ap / sp + b[0]);
}

// ---------------------------------------------------------------------------
extern "C" void kernel_launch(void* const* d_in, const int* in_sizes, int n_in,
                              void* d_out, int out_size, void* d_ws, size_t ws_size,
                              hipStream_t stream) {
  const float* feat     = (const float*)d_in[0];
  const int*   node_ids = (const int*)d_in[1];
  const int*   src      = (const int*)d_in[2];
  const int*   dst      = (const int*)d_in[3];
  const float* emb      = (const float*)d_in[4];
  const float* dense_w  = (const float*)d_in[5];
  const float* dense_b  = (const float*)d_in[6];
  const float* g1_w     = (const float*)d_in[7];
  const float* g1_al    = (const float*)d_in[8];
  const float* g1_ar    = (const float*)d_in[9];
  const float* g1_b     = (const float*)d_in[10];
  const float* g2_w     = (const float*)d_in[11];
  const float* g2_al    = (const float*)d_in[12];
  const float* g2_ar    = (const float*)d_in[13];
  const float* g2_b     = (const float*)d_in[14];
  const float* out_w    = (const float*)d_in[15];
  const float* out_al   = (const float*)d_in[16];
  const float* out_ar   = (const float*)d_in[17];
  const float* out_b    = (const float*)d_in[18];
  const int n = in_sizes[0] / 64;   // 50000
  const int e = in_sizes[2];        // 1600000

  const int ncb = (n + CBG - 1) / CBG;
  int lg = 0;
  while ((1 << lg) < n) lg++;
  const int sshift = lg > 3 ? lg - 3 : 0;   // src block = src >> sshift, <= 8 blocks

  char* ws = (char*)d_ws;
  size_t off = 0;
  auto alloc = [&](size_t bytes) -> void* {
    void* p = ws + off;
    off += (bytes + 255) & ~(size_t)255;
    return p;
  };
  uint32_t* Hp       = (uint32_t*)alloc((size_t)n * 128 * 4);
  size_t zp_bytes    = (size_t)n * 64 * 4;
  size_t tmp_bytes   = (size_t)ncb * CAPC * 4;
  uint32_t* zp       = (uint32_t*)alloc(zp_bytes > tmp_bytes ? zp_bytes : tmp_bytes);
  uint32_t* tmp      = zp;
  float2*   el2      = (float2*)alloc((size_t)n * 8);
  float2*   er2      = (float2*)alloc((size_t)n * 8);
  float*    z3       = (float*)alloc((size_t)n * 4);
  float*    el3      = (float*)alloc((size_t)n * 4);
  float*    er3      = (float*)alloc((size_t)n * 4);
  int*      scount   = (int*)alloc((size_t)ncb * 4);
  int*      row_start= (int*)alloc((size_t)(n + 1) * 4);
  int*      csr_src  = (int*)alloc((size_t)e * 4);
  short*    Wd_hi    = (short*)alloc(2048 * 8 * 2);
  short*    Wd_lo    = (short*)alloc(2048 * 8 * 2);
  short*    W1_hi    = (short*)alloc(2048 * 8 * 2);
  short*    W1_lo    = (short*)alloc(2048 * 8 * 2);
  short*    W2_hi    = (short*)alloc(2048 * 8 * 2);
  short*    W2_lo    = (short*)alloc(2048 * 8 * 2);
  // fallback-only buffers
  int*      cnt      = (int*)alloc((size_t)n * 4);
  int*      cursor   = (int*)alloc((size_t)n * 4);
  const int nblk     = (n + 1023) / 1024;
  int*      bsum     = (int*)alloc((size_t)nblk * 4);

  const int mmgrid = (n + 63) / 64;
  const int ngrid4 = (n + 3) / 4;
  const int ngrid8 = (n + 7) / 8;

  // prep: W split+swizzle + scount zero (one launch)
  prep_kernel<<<25, 256, 0, stream>>>(dense_w, g1_w, g2_w,
                                      Wd_hi, Wd_lo, W1_hi, W1_lo, W2_hi, W2_lo,
                                      scount, ncb);

  if (n < 65536) {
    const int natile = (e + TILE - 1) / TILE;
    bucketA_kernel<<<natile, 256, 0, stream>>>(src, dst, scount, tmp, e, ncb);
    // fused: bucketB (first ncb blocks) + dense GEMM (remaining mmgrid blocks)
    mfmm0_bktB_kernel<<<ncb + mmgrid, 256, 0, stream>>>(
        tmp, scount, row_start, csr_src, ncb,
        Wd_hi, Wd_lo, dense_b, Hp, n, ncb, e, sshift, emb, node_ids, feat);
  } else {
    hipMemsetAsync(cnt, 0, (size_t)n * 4, stream);
    hipMemsetAsync(cursor, 0, (size_t)n * 4, stream);
    hist_kernel<<<2048, 256, 0, stream>>>(dst, cnt, e);
    scan1_kernel<<<nblk, 1024, 0, stream>>>(cnt, row_start, bsum, n);
    scan2_kernel<<<1, 64, 0, stream>>>(bsum, nblk);
    scan3_kernel<<<(n + 255) / 256, 256, 0, stream>>>(row_start, bsum, n, e);
    scatter_kernel<<<2048, 256, 0, stream>>>(src, dst, row_start, cursor, csr_src, e);
    mfmm0_bktB_kernel<<<mmgrid, 256, 0, stream>>>(
        tmp, scount, row_start, csr_src, 0,
        Wd_hi, Wd_lo, dense_b, Hp, n, ncb, e, sshift, emb, node_ids, feat);
  }

  // GAT layer 1
  mfmm1_kernel<<<mmgrid, 256, 0, stream>>>(Hp, W1_hi, W1_lo, zp, el2, er2,
                                           g1_al, g1_ar, n);
  agg12_kernel<<<ngrid4, 256, 0, stream>>>(zp, el2, er2, row_start, csr_src, g1_b, Hp,
                                           nullptr, nullptr, nullptr, nullptr, nullptr,
                                           nullptr, n, 0);
  // GAT layer 2 (+ fused output-layer z3/el3/er3)
  mfmm1_kernel<<<mmgrid, 256, 0, stream>>>(Hp, W2_hi, W2_lo, zp, el2, er2,
                                           g2_al, g2_ar, n);
  agg12_kernel<<<ngrid4, 256, 0, stream>>>(zp, el2, er2, row_start, csr_src, g2_b, nullptr,
                                           out_w, out_al, out_ar, z3, el3, er3, n, 1);
  // output GAT layer aggregation
  agg3_kernel<<<ngrid8, 256, 0, stream>>>(z3, el3, er3, row_start, csr_src, out_b,
                                          (float*)d_out, n);
}

// Round 12
// 232.652 us; speedup vs baseline: 1.1428x; 1.0009x over previous
//
#include <hip/hip_runtime.h>
#include <cfloat>
#include <cmath>

// ---------------------------------------------------------------------------
// UncertaintyGAT. Round-12: r10 launch structure (verified safe w.r.t. the
// zp<->tmp alias: bucketB only ever co-runs with mfmm<0>, which writes Hp) +
// agg12 VALU diet only (r11's crash was the bucketB||mfmm<1> fusion racing
// the zp=tmp alias, NOT the agg12 change):
//   phase-1 stores pre-scaled byte offsets (s<<8) and per-head split exp
//   tables; phase-2 uses one-add addressing and a broadcast per-head x read
//   (no cndmask, no per-lane lshl_add chain). 8-unroll/32VGPR kept (r7/r8).
// ---------------------------------------------------------------------------

#define CBG 256
#define CAPC 12288
#define TILE 4096
#define BIMG 10240

typedef __attribute__((ext_vector_type(8))) short short8v;
typedef __attribute__((ext_vector_type(4))) float f32x4;

__device__ __forceinline__ float lrelu(float x) { return x > 0.f ? x : 0.2f * x; }

__device__ __forceinline__ uint32_t bf16_rne(float f) {
  uint32_t u = __float_as_uint(f);
  return (u + 0x7fffu + ((u >> 16) & 1u)) >> 16;
}
__device__ __forceinline__ uint32_t pack_hilo(float v) {
  uint32_t h = bf16_rne(v);
  float r = v - __uint_as_float(h << 16);
  return (h << 16) | bf16_rne(r);
}

// ---------------- prep: W split+swizzle (blocks 0..23) + scount zero -------
__global__ __launch_bounds__(256) void prep_kernel(
    const float* __restrict__ W0, const float* __restrict__ W1,
    const float* __restrict__ W2, short* __restrict__ Whi0,
    short* __restrict__ Wlo0, short* __restrict__ Whi1, short* __restrict__ Wlo1,
    short* __restrict__ Whi2, short* __restrict__ Wlo2,
    int* __restrict__ scount, int ncb) {
  if (blockIdx.x >= 24) {
    for (int i = threadIdx.x; i < ncb; i += 256) scount[i] = 0;
    return;
  }
  int which = blockIdx.x >> 3;
  const float* W = which == 0 ? W0 : (which == 1 ? W1 : W2);
  short* Whi = which == 0 ? Whi0 : (which == 1 ? Whi1 : Whi2);
  short* Wlo = which == 0 ? Wlo0 : (which == 1 ? Wlo1 : Wlo2);
  int fid = (blockIdx.x & 7) * 256 + threadIdx.x;  // 0..2047
  int lane = fid & 63;
  int cq = fid >> 6;
  int q = cq >> 3, c = cq & 7;
  int col = c * 16 + (lane & 15);
  int k0 = q * 32 + (lane >> 4) * 8;
#pragma unroll
  for (int j = 0; j < 8; j++) {
    float v = W[(k0 + j) * 128 + col];
    uint32_t h = bf16_rne(v);
    float r = v - __uint_as_float(h << 16);
    Whi[fid * 8 + j] = (short)h;
    Wlo[fid * 8 + j] = (short)bf16_rne(r);
  }
}

// ---------------- CSR build (n < 65536 path) ----------------
__global__ __launch_bounds__(256) void bucketA_kernel(
    const int* __restrict__ src, const int* __restrict__ dst,
    int* __restrict__ scount, uint32_t* __restrict__ tmp, int e, int ncb) {
  __shared__ int cnt[256];
  __shared__ int lscan[256];
  __shared__ int gbase[256];
  __shared__ uint32_t image[TILE];
  const int t = threadIdx.x;
  const int e0 = blockIdx.x * TILE;
  const int ne = min(TILE, e - e0);

  for (int i = t; i < 256; i += 256) cnt[i] = 0;
  __syncthreads();
  for (int i = t; i < ne; i += 256) atomicAdd(&cnt[dst[e0 + i] >> 8], 1);
  __syncthreads();
  if (t < 64) {
    int carry = 0;
    for (int base = 0; base < ncb; base += 64) {
      int idx = base + t;
      int c = (idx < ncb) ? cnt[idx] : 0;
      int v = c;
#pragma unroll
      for (int off = 1; off < 64; off <<= 1) {
        int u = __shfl_up(v, off, 64);
        if (t >= off) v += u;
      }
      if (idx < ncb) lscan[idx] = carry + v - c;
      carry += __shfl(v, 63, 64);
    }
  }
  __syncthreads();
  for (int b = t; b < ncb; b += 256)
    gbase[b] = (cnt[b] > 0) ? atomicAdd(&scount[b], cnt[b]) : 0;
  __syncthreads();
  for (int b = t; b < ncb; b += 256) cnt[b] = 0;
  __syncthreads();
  for (int i = t; i < ne; i += 256) {
    int d = dst[e0 + i], s = src[e0 + i];
    int b = d >> 8;
    int r = atomicAdd(&cnt[b], 1);
    image[lscan[b] + r] =
        (uint32_t)s | ((uint32_t)(d & 255) << 16) | ((uint32_t)b << 24);
  }
  __syncthreads();
  for (int j = t; j < ne; j += 256) {
    uint32_t w = image[j];
    int b = w >> 24;
    int pos = gbase[b] + (j - lscan[b]);
    if (pos < CAPC) tmp[(size_t)b * CAPC + pos] = w & 0xFFFFFFu;
  }
}

// ---------------- bucketB body: key = dst_local*8 + src_block --------------
__device__ __forceinline__ void bucketB_body(
    int b, char* smem, const uint32_t* __restrict__ tmp,
    const int* __restrict__ scount, int* __restrict__ row_start,
    int* __restrict__ csr_src, int n, int ncb, int e, int sshift) {
  int* cnt2 = (int*)smem;                      // 2048 (hist -> cursor)
  int* wsum = cnt2 + 2048;                     // 4
  int* s_base = wsum + 4;                      // 1
  uint32_t* image = (uint32_t*)(smem + 8224);  // BIMG
  const int t = threadIdx.x, lane = t & 63, wid = t >> 6;

  if (t < 64) {
    int part = 0;
    for (int idx = lane; idx < b; idx += 64) part += scount[idx];
#pragma unroll
    for (int off = 32; off; off >>= 1) part += __shfl_xor(part, off, 64);
    if (lane == 0) *s_base = part;
  }
#pragma unroll
  for (int j = 0; j < 8; j++) cnt2[t * 8 + j] = 0;
  __syncthreads();
  const int total = min(scount[b], CAPC);
  const int base = *s_base;
  const uint32_t* strm = tmp + (size_t)b * CAPC;

  for (int i = t; i < total; i += 256) {
    uint32_t w = strm[i];
    int key = (((w >> 16) & 255) << 3) + ((w & 0xFFFFu) >> sshift);
    atomicAdd(&cnt2[key], 1);
  }
  __syncthreads();
  int c8[8];
  int run = 0;
#pragma unroll
  for (int j = 0; j < 8; j++) { int x = cnt2[t * 8 + j]; c8[j] = run; run += x; }
  int c = run, v = c;
#pragma unroll
  for (int off = 1; off < 64; off <<= 1) {
    int u = __shfl_up(v, off, 64);
    if (lane >= off) v += u;
  }
  if (lane == 63) wsum[wid] = v;
  __syncthreads();
  if (t == 0) {
    int acc = 0;
#pragma unroll
    for (int w = 0; w < 4; w++) { int x = wsum[w]; wsum[w] = acc; acc += x; }
  }
  __syncthreads();
  int ex = wsum[wid] + v - c;
#pragma unroll
  for (int j = 0; j < 8; j++) cnt2[t * 8 + j] = ex + c8[j];
  int d = b * CBG + t;
  if (d < n) row_start[d] = base + ex;
  if (b == 0 && t == 0) row_start[n] = e;
  __syncthreads();
  for (int i = t; i < total; i += 256) {
    uint32_t w = strm[i];
    uint32_t s = w & 0xFFFFu;
    int key = (((w >> 16) & 255) << 3) + (s >> sshift);
    int pos = atomicAdd(&cnt2[key], 1);
    if (pos < BIMG) image[pos] = s;
    else csr_src[base + pos] = (int)s;
  }
  __syncthreads();
  const int lim = total < BIMG ? total : BIMG;
  for (int j = t; j < lim; j += 256) csr_src[base + j] = (int)image[j];
}

// ---------------- MFMA GEMM body (uses caller LDS; 34.8KB) ----------------
template <int MODE>
__device__ __forceinline__ void mfmm_body(
    int bid, char* smem,
    const uint32_t* __restrict__ Xp, const short* __restrict__ Whi,
    const short* __restrict__ Wlo, const float* __restrict__ bias,
    uint32_t* __restrict__ Hp, uint32_t* __restrict__ zp,
    float2* __restrict__ el2, float2* __restrict__ er2,
    const float* __restrict__ al, const float* __restrict__ ar, int n,
    const float* __restrict__ emb, const int* __restrict__ ids,
    const float* __restrict__ feat) {
  short* Ahi = (short*)smem;
  short* Alo = Ahi + 64 * 136;
  const int t = threadIdx.x;
  const int nb = bid * 64;

  for (int idx = t; idx < 64 * 32; idx += 256) {
    int nl = idx >> 5, k4 = (idx & 31) << 2;
    int node = nb + nl;
    uint32_t h01 = 0, h23 = 0, l01 = 0, l23 = 0;
    if (node < n) {
      if (MODE == 1) {
        uint4 w = *(const uint4*)&Xp[(size_t)node * 128 + k4];
        h01 = (w.x >> 16) | (w.y & 0xffff0000u);
        l01 = (w.x & 0xffffu) | (w.y << 16);
        h23 = (w.z >> 16) | (w.w & 0xffff0000u);
        l23 = (w.z & 0xffffu) | (w.w << 16);
      } else {
        float4 v;
        if (k4 < 64) v = *(const float4*)&emb[(size_t)ids[node] * 64 + k4];
        else         v = *(const float4*)&feat[(size_t)node * 64 + (k4 - 64)];
        uint32_t a0 = bf16_rne(v.x), a1 = bf16_rne(v.y);
        uint32_t a2 = bf16_rne(v.z), a3 = bf16_rne(v.w);
        h01 = a0 | (a1 << 16);
        h23 = a2 | (a3 << 16);
        l01 = bf16_rne(v.x - __uint_as_float(a0 << 16)) |
              (bf16_rne(v.y - __uint_as_float(a1 << 16)) << 16);
        l23 = bf16_rne(v.z - __uint_as_float(a2 << 16)) |
              (bf16_rne(v.w - __uint_as_float(a3 << 16)) << 16);
      }
    }
    *(uint2*)&Ahi[nl * 136 + k4] = make_uint2(h01, h23);
    *(uint2*)&Alo[nl * 136 + k4] = make_uint2(l01, l23);
  }
  __syncthreads();

  const int lane = t & 63, wv = t >> 6;
  const int r16 = lane & 15, g = lane >> 4;
  const int arow = (wv * 16 + r16) * 136;

  f32x4 acc[8];
#pragma unroll
  for (int c = 0; c < 8; c++) acc[c] = (f32x4){0.f, 0.f, 0.f, 0.f};

#pragma unroll
  for (int q = 0; q < 4; q++) {
    int ka = q * 32 + g * 8;
    short8v ahi = *(const short8v*)&Ahi[arow + ka];
    short8v alo = *(const short8v*)&Alo[arow + ka];
#pragma unroll
    for (int c = 0; c < 8; c++) {
      short8v bhi = *(const short8v*)&Whi[(((q * 8 + c) * 64) + lane) * 8];
      short8v blo = *(const short8v*)&Wlo[(((q * 8 + c) * 64) + lane) * 8];
      acc[c] = __builtin_amdgcn_mfma_f32_16x16x32_bf16(ahi, bhi, acc[c], 0, 0, 0);
      acc[c] = __builtin_amdgcn_mfma_f32_16x16x32_bf16(ahi, blo, acc[c], 0, 0, 0);
      acc[c] = __builtin_amdgcn_mfma_f32_16x16x32_bf16(alo, bhi, acc[c], 0, 0, 0);
    }
  }

  const int node_base = nb + wv * 16;
  if (MODE == 0) {
#pragma unroll
    for (int c = 0; c < 8; c++) {
      int col = c * 16 + r16;
      float bv = bias[col];
#pragma unroll
      for (int r = 0; r < 4; r++) {
        int node = node_base + g * 4 + r;
        if (node < n) {
          float v = fmaxf(acc[c][r] + bv, 0.f);
          Hp[(size_t)node * 128 + col] = pack_hilo(v);
        }
      }
    }
  } else {
    float p0l[4] = {0, 0, 0, 0}, p1l[4] = {0, 0, 0, 0};
    float p0r[4] = {0, 0, 0, 0}, p1r[4] = {0, 0, 0, 0};
#pragma unroll
    for (int c = 0; c < 8; c++) {
      int col = c * 16 + r16;
      float av = al[col], rv = ar[col];
#pragma unroll
      for (int r = 0; r < 4; r++) {
        if (c < 4) { p0l[r] = fmaf(acc[c][r], av, p0l[r]); p0r[r] = fmaf(acc[c][r], rv, p0r[r]); }
        else       { p1l[r] = fmaf(acc[c][r], av, p1l[r]); p1r[r] = fmaf(acc[c][r], rv, p1r[r]); }
      }
    }
#pragma unroll
    for (int c = 0; c < 8; c++) {
#pragma unroll
      for (int r = 0; r < 4; r++) {
        float other = __shfl_xor(acc[c][r], 1, 64);
        int node = node_base + g * 4 + r;
        if (!(lane & 1) && node < n) {
          uint32_t w = bf16_rne(acc[c][r]) | (bf16_rne(other) << 16);
          zp[(size_t)node * 64 + c * 8 + (r16 >> 1)] = w;
        }
      }
    }
#pragma unroll
    for (int off = 1; off < 16; off <<= 1) {
#pragma unroll
      for (int r = 0; r < 4; r++) {
        p0l[r] += __shfl_xor(p0l[r], off, 64);
        p1l[r] += __shfl_xor(p1l[r], off, 64);
        p0r[r] += __shfl_xor(p0r[r], off, 64);
        p1r[r] += __shfl_xor(p1r[r], off, 64);
      }
    }
    if (r16 == 0) {
#pragma unroll
      for (int r = 0; r < 4; r++) {
        int node = node_base + g * 4 + r;
        if (node < n) {
          el2[node] = make_float2(p0l[r], p1l[r]);
          er2[node] = make_float2(p0r[r], p1r[r]);
        }
      }
    }
  }
}

// ---- fused: bucketB (blocks [0,ncbB)) + dense GEMM (writes Hp only; safe
// w.r.t. the zp<->tmp alias since zp is first written by the LATER mfmm1) ----
__global__ __launch_bounds__(256) void mfmm0_bktB_kernel(
    const uint32_t* __restrict__ tmp, const int* __restrict__ scount,
    int* __restrict__ row_start, int* __restrict__ csr_src, int ncbB,
    const short* __restrict__ Whi, const short* __restrict__ Wlo,
    const float* __restrict__ bias, uint32_t* __restrict__ Hp, int n, int ncb,
    int e, int sshift, const float* __restrict__ emb, const int* __restrict__ ids,
    const float* __restrict__ feat) {
  __shared__ __align__(16) char smem[49200];
  if ((int)blockIdx.x < ncbB) {
    bucketB_body(blockIdx.x, smem, tmp, scount, row_start, csr_src, n, ncb, e,
                 sshift);
  } else {
    mfmm_body<0>(blockIdx.x - ncbB, smem, nullptr, Whi, Wlo, bias, Hp,
                 nullptr, nullptr, nullptr, nullptr, nullptr, n, emb, ids, feat);
  }
}

__global__ __launch_bounds__(256) void mfmm1_kernel(
    const uint32_t* __restrict__ Xp, const short* __restrict__ Whi,
    const short* __restrict__ Wlo, uint32_t* __restrict__ zp,
    float2* __restrict__ el2, float2* __restrict__ er2,
    const float* __restrict__ al, const float* __restrict__ ar, int n) {
  __shared__ __align__(16) char smem[34816];
  mfmm_body<1>(blockIdx.x, smem, Xp, Whi, Wlo, nullptr, nullptr, zp, el2, er2,
               al, ar, n, nullptr, nullptr, nullptr);
}

// ---------------- fallback path (n >= 65536) ----------------
__global__ void hist_kernel(const int* __restrict__ dst, int* __restrict__ cnt, int e) {
  for (int i = blockIdx.x * blockDim.x + threadIdx.x; i < e; i += gridDim.x * blockDim.x)
    atomicAdd(&cnt[dst[i]], 1);
}
__global__ void scatter_kernel(const int* __restrict__ src, const int* __restrict__ dst,
                               const int* __restrict__ row_start, int* __restrict__ cursor,
                               int* __restrict__ csr_src, int e) {
  for (int i = blockIdx.x * blockDim.x + threadIdx.x; i < e; i += gridDim.x * blockDim.x) {
    int d = dst[i];
    int pos = atomicAdd(&cursor[d], 1);
    csr_src[row_start[d] + pos] = src[i];
  }
}
__global__ __launch_bounds__(1024) void scan1_kernel(const int* __restrict__ cnt,
                                                     int* __restrict__ row_start,
                                                     int* __restrict__ bsum, int n) {
  __shared__ int wsum[16];
  const int t = threadIdx.x, lane = t & 63, wid = t >> 6;
  int i = blockIdx.x * 1024 + t;
  int c = (i < n) ? cnt[i] : 0;
  int v = c;
#pragma unroll
  for (int off = 1; off < 64; off <<= 1) {
    int u = __shfl_up(v, off, 64);
    if (lane >= off) v += u;
  }
  if (lane == 63) wsum[wid] = v;
  __syncthreads();
  if (t == 0) {
    int acc = 0;
#pragma unroll
    for (int w = 0; w < 16; w++) { int x = wsum[w]; wsum[w] = acc; acc += x; }
    bsum[blockIdx.x] = acc;
  }
  __syncthreads();
  if (i < n) row_start[i] = wsum[wid] + v - c;
}
__global__ __launch_bounds__(64) void scan2_kernel(int* __restrict__ bsum, int nb) {
  const int lane = threadIdx.x;
  int carry = 0;
  for (int base = 0; base < nb; base += 64) {
    int idx = base + lane;
    int c = (idx < nb) ? bsum[idx] : 0;
    int v = c;
#pragma unroll
    for (int off = 1; off < 64; off <<= 1) {
      int u = __shfl_up(v, off, 64);
      if (lane >= off) v += u;
    }
    if (idx < nb) bsum[idx] = carry + v - c;
    carry += __shfl(v, 63, 64);
  }
}
__global__ void scan3_kernel(int* __restrict__ row_start, const int* __restrict__ bsum,
                             int n, int e) {
  int i = blockIdx.x * blockDim.x + threadIdx.x;
  if (i < n) row_start[i] += bsum[i >> 10];
  if (i == 0) row_start[n] = e;
}

// ---------------- GAT aggregation (wave per dst node) ----------------------
// phase-1: full-wave float2 el2 gather; stores pre-scaled byte offset s<<8
// and per-head split exp tables. phase-2: 8-unroll, one-add addressing,
// broadcast per-head x read (no cndmask). 32 VGPR operating point (r7/r8).
#define CAP 256
__global__ __launch_bounds__(256) void agg12_kernel(
    const uint32_t* __restrict__ zp, const float2* __restrict__ el2,
    const float2* __restrict__ er2, const int* __restrict__ row_start,
    const int* __restrict__ csr_src, const float* __restrict__ bias,
    uint32_t* __restrict__ Hp,
    const float* __restrict__ ow, const float* __restrict__ oal,
    const float* __restrict__ oar, float* __restrict__ z3,
    float* __restrict__ el3, float* __restrict__ er3, int n, int fuse_out) {
  __shared__ float ecf[4][2][CAP];
  __shared__ int sc[4][CAP];
  const int w = threadIdx.x >> 6, lane = threadIdx.x & 63;
  const int node = blockIdx.x * 4 + w;
  const bool valid = node < n;
  int rs = 0, deg = 0;
  float er0 = 0.f, er1 = 0.f;
  if (valid) {
    rs = row_start[node];
    deg = row_start[node + 1] - rs;
    float2 e2 = er2[node];
    er0 = e2.x; er1 = e2.y;
  }
  const int cdeg = deg < CAP ? deg : CAP;

  float sp0 = 0.f, sp1 = 0.f;
  for (int i = lane; i < deg; i += 64) {
    int s = csr_src[rs + i];
    float2 l = el2[s];
    float x0 = __expf(lrelu(l.x + er0));
    float x1 = __expf(lrelu(l.y + er1));
    if (i < CAP) { sc[w][i] = s << 8; ecf[w][0][i] = x0; ecf[w][1][i] = x1; }
    sp0 += x0; sp1 += x1;
  }
#pragma unroll
  for (int off = 32; off; off >>= 1) {
    sp0 += __shfl_xor(sp0, off, 64);
    sp1 += __shfl_xor(sp1, off, 64);
  }
  __syncthreads();

  const float* exh = ecf[w][lane >> 5];
  const char* zpB = (const char*)zp + (size_t)lane * 4;
  float ae = 0.f, ao = 0.f;
  int i = 0;
  for (; i + 8 <= cdeg; i += 8) {
    uint32_t zw[8];
    float xh[8];
#pragma unroll
    for (int u = 0; u < 8; u++) {
      int off = sc[w][i + u];
      xh[u] = exh[i + u];
      zw[u] = *(const uint32_t*)(zpB + off);
    }
#pragma unroll
    for (int u = 0; u < 8; u++) {
      ae = fmaf(xh[u], __uint_as_float(zw[u] << 16), ae);
      ao = fmaf(xh[u], __uint_as_float(zw[u] & 0xffff0000u), ao);
    }
  }
  for (; i < cdeg; i++) {
    int off = sc[w][i];
    float x = exh[i];
    uint32_t zw = *(const uint32_t*)(zpB + off);
    ae = fmaf(x, __uint_as_float(zw << 16), ae);
    ao = fmaf(x, __uint_as_float(zw & 0xffff0000u), ao);
  }
  for (; i < deg; i++) {  // beyond-CAP tail (not hit for this graph)
    int s = csr_src[rs + i];
    float2 l = el2[s];
    float x0 = __expf(lrelu(l.x + er0));
    float x1 = __expf(lrelu(l.y + er1));
    float x = (lane < 32) ? x0 : x1;
    uint32_t zw = *(const uint32_t*)(zpB + ((size_t)s << 8));
    ae = fmaf(x, __uint_as_float(zw << 16), ae);
    ao = fmaf(x, __uint_as_float(zw & 0xffff0000u), ao);
  }

  if (valid) {
    float sp = (lane < 32) ? sp0 : sp1;
    float2 b2 = reinterpret_cast<const float2*>(bias)[lane];
    float oe, oo;
    if (deg == 0) { oe = b2.x; oo = b2.y; }
    else { oe = ae / sp + b2.x; oo = ao / sp + b2.y; }
    oe = fmaxf(oe, 0.f);
    oo = fmaxf(oo, 0.f);
    if (!fuse_out) {
      *(uint2*)&Hp[(size_t)node * 128 + 2 * lane] =
          make_uint2(pack_hilo(oe), pack_hilo(oo));
    } else {
      float2 w2 = reinterpret_cast<const float2*>(ow)[lane];
      float d = oe * w2.x + oo * w2.y;
#pragma unroll
      for (int off = 32; off; off >>= 1) d += __shfl_xor(d, off, 64);
      if (lane == 0) {
        z3[node] = d;
        el3[node] = d * oal[0];
        er3[node] = d * oar[0];
      }
    }
  }
}

// ---------------- output GAT layer: 32-lane group per node -----------------
__global__ __launch_bounds__(256) void agg3_kernel(
    const float* __restrict__ z3, const float* __restrict__ el3,
    const float* __restrict__ er3, const int* __restrict__ row_start,
    const int* __restrict__ csr_src, const float* __restrict__ b,
    float* __restrict__ out, int n) {
  int node = blockIdx.x * 8 + (threadIdx.x >> 5);
  int l32 = threadIdx.x & 31;
  if (node >= n) return;
  int rs = row_start[node];
  int deg = row_start[node + 1] - rs;
  float er = er3[node];
  float sp = 0.f, ap = 0.f;
  for (int i = l32; i < deg; i += 32) {
    int s = csr_src[rs + i];
    float ex = __expf(lrelu(el3[s] + er));
    sp += ex;
    ap = fmaf(ex, z3[s], ap);
  }
#pragma unroll
  for (int off = 16; off; off >>= 1) {
    sp += __shfl_xor(sp, off, 64);
    ap += __shfl_xor(ap, off, 64);
  }
  if (l32 == 0) out[node] = (deg == 0) ? b[0] : (ap / sp + b[0]);
}

// ---------------------------------------------------------------------------
extern "C" void kernel_launch(void* const* d_in, const int* in_sizes, int n_in,
                              void* d_out, int out_size, void* d_ws, size_t ws_size,
                              hipStream_t stream) {
  const float* feat     = (const float*)d_in[0];
  const int*   node_ids = (const int*)d_in[1];
  const int*   src      = (const int*)d_in[2];
  const int*   dst      = (const int*)d_in[3];
  const float* emb      = (const float*)d_in[4];
  const float* dense_w  = (const float*)d_in[5];
  const float* dense_b  = (const float*)d_in[6];
  const float* g1_w     = (const float*)d_in[7];
  const float* g1_al    = (const float*)d_in[8];
  const float* g1_ar    = (const float*)d_in[9];
  const float* g1_b     = (const float*)d_in[10];
  const float* g2_w     = (const float*)d_in[11];
  const float* g2_al    = (const float*)d_in[12];
  const float* g2_ar    = (const float*)d_in[13];
  const float* g2_b     = (const float*)d_in[14];
  const float* out_w    = (const float*)d_in[15];
  const float* out_al   = (const float*)d_in[16];
  const float* out_ar   = (const float*)d_in[17];
  const float* out_b    = (const float*)d_in[18];
  const int n = in_sizes[0] / 64;   // 50000
  const int e = in_sizes[2];        // 1600000

  const int ncb = (n + CBG - 1) / CBG;
  int lg = 0;
  while ((1 << lg) < n) lg++;
  const int sshift = lg > 3 ? lg - 3 : 0;

  char* ws = (char*)d_ws;
  size_t off = 0;
  auto alloc = [&](size_t bytes) -> void* {
    void* p = ws + off;
    off += (bytes + 255) & ~(size_t)255;
    return p;
  };
  uint32_t* Hp       = (uint32_t*)alloc((size_t)n * 128 * 4);
  size_t zp_bytes    = (size_t)n * 64 * 4;
  size_t tmp_bytes   = (size_t)ncb * CAPC * 4;
  uint32_t* zp       = (uint32_t*)alloc(zp_bytes > tmp_bytes ? zp_bytes : tmp_bytes);
  uint32_t* tmp      = zp;   // alias: tmp dead before zp first written (mfmm1)
  float2*   el2      = (float2*)alloc((size_t)n * 8);
  float2*   er2      = (float2*)alloc((size_t)n * 8);
  float*    z3       = (float*)alloc((size_t)n * 4);
  float*    el3      = (float*)alloc((size_t)n * 4);
  float*    er3      = (float*)alloc((size_t)n * 4);
  int*      scount   = (int*)alloc((size_t)ncb * 4);
  int*      row_start= (int*)alloc((size_t)(n + 1) * 4);
  int*      csr_src  = (int*)alloc((size_t)e * 4);
  short*    Wd_hi    = (short*)alloc(2048 * 8 * 2);
  short*    Wd_lo    = (short*)alloc(2048 * 8 * 2);
  short*    W1_hi    = (short*)alloc(2048 * 8 * 2);
  short*    W1_lo    = (short*)alloc(2048 * 8 * 2);
  short*    W2_hi    = (short*)alloc(2048 * 8 * 2);
  short*    W2_lo    = (short*)alloc(2048 * 8 * 2);
  // fallback-only buffers
  int*      cnt      = (int*)alloc((size_t)n * 4);
  int*      cursor   = (int*)alloc((size_t)n * 4);
  const int nblk     = (n + 1023) / 1024;
  int*      bsum     = (int*)alloc((size_t)nblk * 4);

  const int mmgrid = (n + 63) / 64;
  const int ngrid4 = (n + 3) / 4;
  const int ngrid8 = (n + 7) / 8;

  // prep: W split+swizzle + scount zero (one launch)
  prep_kernel<<<25, 256, 0, stream>>>(dense_w, g1_w, g2_w,
                                      Wd_hi, Wd_lo, W1_hi, W1_lo, W2_hi, W2_lo,
                                      scount, ncb);

  if (n < 65536) {
    const int natile = (e + TILE - 1) / TILE;
    bucketA_kernel<<<natile, 256, 0, stream>>>(src, dst, scount, tmp, e, ncb);
    // fused: bucketB (first ncb blocks) + dense GEMM (remaining mmgrid blocks)
    mfmm0_bktB_kernel<<<ncb + mmgrid, 256, 0, stream>>>(
        tmp, scount, row_start, csr_src, ncb,
        Wd_hi, Wd_lo, dense_b, Hp, n, ncb, e, sshift, emb, node_ids, feat);
  } else {
    hipMemsetAsync(cnt, 0, (size_t)n * 4, stream);
    hipMemsetAsync(cursor, 0, (size_t)n * 4, stream);
    hist_kernel<<<2048, 256, 0, stream>>>(dst, cnt, e);
    scan1_kernel<<<nblk, 1024, 0, stream>>>(cnt, row_start, bsum, n);
    scan2_kernel<<<1, 64, 0, stream>>>(bsum, nblk);
    scan3_kernel<<<(n + 255) / 256, 256, 0, stream>>>(row_start, bsum, n, e);
    scatter_kernel<<<2048, 256, 0, stream>>>(src, dst, row_start, cursor, csr_src, e);
    mfmm0_bktB_kernel<<<mmgrid, 256, 0, stream>>>(
        tmp, scount, row_start, csr_src, 0,
        Wd_hi, Wd_lo, dense_b, Hp, n, ncb, e, sshift, emb, node_ids, feat);
  }

  // GAT layer 1
  mfmm1_kernel<<<mmgrid, 256, 0, stream>>>(Hp, W1_hi, W1_lo, zp, el2, er2,
                                           g1_al, g1_ar, n);
  agg12_kernel<<<ngrid4, 256, 0, stream>>>(zp, el2, er2, row_start, csr_src, g1_b, Hp,
                                           nullptr, nullptr, nullptr, nullptr, nullptr,
                                           nullptr, n, 0);
  // GAT layer 2 (+ fused output-layer z3/el3/er3)
  mfmm1_kernel<<<mmgrid, 256, 0, stream>>>(Hp, W2_hi, W2_lo, zp, el2, er2,
                                           g2_al, g2_ar, n);
  agg12_kernel<<<ngrid4, 256, 0, stream>>>(zp, el2, er2, row_start, csr_src, g2_b, nullptr,
                                           out_w, out_al, out_ar, z3, el3, er3, n, 1);
  // output GAT layer aggregation
  agg3_kernel<<<ngrid8, 256, 0, stream>>>(z3, el3, er3, row_start, csr_src, out_b,
                                          (float*)d_out, n);
}